// Round 5
// baseline (1291.257 us; speedup 1.0000x reference)
//
#include <hip/hip_runtime.h>
#include <math.h>

#define NN 8192
#define NPD 128
#define F_IN 128
#define DD 512
#define HH 1024
#define EE 131072
#define NDOC 64
#define NPAIR 32

typedef __attribute__((ext_vector_type(8))) short bf16x8;
typedef __attribute__((ext_vector_type(4))) float f32x4;
typedef const __attribute__((address_space(1))) void* gas_ptr;
typedef __attribute__((address_space(3))) void* las_ptr;

__device__ __forceinline__ unsigned short f2b(float f) {
    union { float f; unsigned u; } v; v.f = f;
    unsigned r = v.u + 0x7fffu + ((v.u >> 16) & 1u);
    return (unsigned short)(r >> 16);
}
__device__ __forceinline__ float b2f_lo(unsigned u) {
    union { unsigned u; float f; } v; v.u = u << 16; return v.f;
}
__device__ __forceinline__ float b2f_hi(unsigned u) {
    union { unsigned u; float f; } v; v.u = u & 0xffff0000u; return v.f;
}

// ---------------------------------------------------------------------------
// Degree / CSR construction
// ---------------------------------------------------------------------------
__global__ void k_zero_cnt(int* __restrict__ cnt) {
    int i = blockIdx.x * 256 + threadIdx.x;
    if (i < NN) cnt[i] = 0;
}

__global__ void k_count(const int* __restrict__ ei, int* __restrict__ cnt) {
    int e = blockIdx.x * 256 + threadIdx.x;
    if (e < EE) atomicAdd(&cnt[ei[EE + e]], 1);
}

// exclusive scan of cnt -> off/pos, plus dinv = rsqrt(cnt+1)
__global__ void k_scan(const int* __restrict__ cnt, int* __restrict__ off,
                       int* __restrict__ pos, float* __restrict__ dinv) {
    __shared__ int part[1024];
    int t = threadIdx.x;
    int loc[8];
    int s = 0;
    int base = t * 8;
#pragma unroll
    for (int j = 0; j < 8; ++j) {
        int c = cnt[base + j];
        dinv[base + j] = rsqrtf((float)c + 1.0f);
        loc[j] = s;
        s += c;
    }
    part[t] = s;
    __syncthreads();
    for (int st = 1; st < 1024; st <<= 1) {
        int v = (t >= st) ? part[t - st] : 0;
        __syncthreads();
        part[t] += v;
        __syncthreads();
    }
    int pre = (t > 0) ? part[t - 1] : 0;
#pragma unroll
    for (int j = 0; j < 8; ++j) {
        int val = pre + loc[j];
        off[base + j] = val;
        pos[base + j] = val;
    }
    if (t == 1023) off[NN] = part[1023];
}

__global__ void k_fill(const int* __restrict__ ei, const float* __restrict__ dinv,
                       int* __restrict__ pos, int* __restrict__ csr_src,
                       float* __restrict__ csr_w) {
    int e = blockIdx.x * 256 + threadIdx.x;
    if (e >= EE) return;
    int r = ei[e];
    int c = ei[EE + e];
    int p = atomicAdd(&pos[c], 1);
    csr_src[p] = r;
    csr_w[p] = dinv[r] * dinv[c];
}

// ---------------------------------------------------------------------------
__global__ void k_cast(const float* __restrict__ in, unsigned short* __restrict__ out,
                       int n) {
    int i = (blockIdx.x * 256 + threadIdx.x) * 4;
    if (i < n) {
        float4 v = *(const float4*)(in + i);
        out[i + 0] = f2b(v.x);
        out[i + 1] = f2b(v.y);
        out[i + 2] = f2b(v.z);
        out[i + 3] = f2b(v.w);
    }
}

// transpose W (K x M fp32) -> Wt (M x K bf16), batched over z with strides.
// grid (M/32, K/32, nz), block (32,8)
__global__ void k_trz(const float* __restrict__ in, unsigned short* __restrict__ out,
                      int K, int M, long sin, long sout) {
    in += (size_t)blockIdx.z * sin;
    out += (size_t)blockIdx.z * sout;
    __shared__ float t[32][33];
    int bx = blockIdx.x * 32;
    int by = blockIdx.y * 32;
    int tx = threadIdx.x, ty = threadIdx.y;
    for (int i = ty; i < 32; i += 8)
        t[i][tx] = in[(size_t)(by + i) * M + bx + tx];
    __syncthreads();
    for (int i = ty; i < 32; i += 8)
        out[(size_t)(bx + i) * K + by + tx] = f2b(t[tx][i]);
}

// ---------------------------------------------------------------------------
// bf16 MFMA GEMM (generalized): C = act(A @ Bt^T + bias)
// A: rows x K (lda), Bt: M x K (ldbt), per-z strides; 128x128 tile, BK=64.
// ACT: 0 none, 1 relu, 2 tanh, 3 scale(1/sqrt(512))
// OMODE: 0 fp32 out, 1 bf16 out, 3 bf16 out but z==2 -> transposed-per-doc
// SWZ: XCD-aware block swizzle (requires gridDim.y % 8 == 0)
// xorb: B z-index = z ^ xorb (cross-doc attention pairing)
// ---------------------------------------------------------------------------
template <int ACT, int OMODE, int SWZ>
__global__ __launch_bounds__(256) void gemm_mfma(
    const unsigned short* __restrict__ A, const unsigned short* __restrict__ Bt,
    const float* __restrict__ bias, void* __restrict__ Cout,
    int K, int lda, int ldbt, int ldc, int mreal,
    long saz, long sbz, long scz, int sbiasz, int xorb) {
    __shared__ unsigned short As[128 * 64];
    __shared__ unsigned short Bs[128 * 64];

    int bx = blockIdx.x, by = blockIdx.y, bz = blockIdx.z;
    if (SWZ) {
        // group blocks so one XCD (linear%8) sweeps all x-tiles over an
        // 8-row y-band before moving on -> A-band + B tiles stay L2-resident
        const int nx = gridDim.x, ny = gridDim.y;
        const int band = ny >> 3;
        int b = (bz * ny + by) * nx + bx;
        const int k = b & 7;
        int s = b >> 3;
        bx = s % nx; s /= nx;
        const int yl = s % band; s /= band;
        bz = s;
        by = k * band + yl;
    }
    const int z = bz;
    A += (size_t)z * saz;
    Bt += (size_t)(z ^ xorb) * sbz;
    if (bias) bias += (size_t)z * sbiasz;

    const int tid = threadIdx.x;
    const int wave = tid >> 6, lane = tid & 63;
    const int m0 = by * 128;
    const int n0 = bx * 128;
    const int wm = (wave & 1) * 64, wn = (wave >> 1) * 64;
    const int lhi = lane >> 4;
    const int llo = lane & 15;
    f32x4 acc[4][4] = {};

    const int srow = lane >> 3;
    const int scol = (lane & 7) * 8;
    const unsigned short* ag = A + (size_t)(m0 + wave * 32 + srow) * lda + scol;
    const unsigned short* bg = Bt + (size_t)(n0 + wave * 32 + srow) * ldbt + scol;
    unsigned short* al = As + wave * 2048;
    unsigned short* bl = Bs + wave * 2048;

    for (int k0 = 0; k0 < K; k0 += 64) {
#pragma unroll
        for (int r = 0; r < 4; ++r) {
            __builtin_amdgcn_global_load_lds((gas_ptr)(ag + k0 + (size_t)r * 8 * lda),
                                             (las_ptr)(al + r * 512), 16, 0, 0);
            __builtin_amdgcn_global_load_lds((gas_ptr)(bg + k0 + (size_t)r * 8 * ldbt),
                                             (las_ptr)(bl + r * 512), 16, 0, 0);
        }
        __syncthreads();
#pragma unroll
        for (int s = 0; s < 2; ++s) {
            bf16x8 af[4], bf[4];
#pragma unroll
            for (int i = 0; i < 4; ++i) {
                af[i] = *(const bf16x8*)(As + (wm + i * 16 + llo) * 64 + s * 32 + lhi * 8);
                bf[i] = *(const bf16x8*)(Bs + (wn + i * 16 + llo) * 64 + s * 32 + lhi * 8);
            }
#pragma unroll
            for (int i = 0; i < 4; ++i)
#pragma unroll
                for (int j = 0; j < 4; ++j)
                    acc[i][j] = __builtin_amdgcn_mfma_f32_16x16x32_bf16(af[i], bf[j],
                                                                        acc[i][j], 0, 0, 0);
        }
        __syncthreads();
    }

    float* Cf = (float*)Cout + (size_t)z * scz;
    unsigned short* Cb = (unsigned short*)Cout + (size_t)z * scz;
#pragma unroll
    for (int j = 0; j < 4; ++j) {
        const int col = n0 + wn + j * 16 + llo;
        if (col < mreal) {
            const float bv = bias ? bias[col] : 0.f;
#pragma unroll
            for (int i = 0; i < 4; ++i) {
                const int row = m0 + wm + i * 16 + lhi * 4;
                const int rloc = wm + i * 16 + lhi * 4;
#pragma unroll
                for (int r = 0; r < 4; ++r) {
                    float v = acc[i][j][r] + bv;
                    if (ACT == 1) v = fmaxf(v, 0.f);
                    if (ACT == 2) v = tanhf(v);
                    if (ACT == 3) v *= 0.044194173824159216f;
                    if (OMODE == 0) {
                        Cf[(size_t)(row + r) * ldc + col] = v;
                    } else if (OMODE == 1) {
                        Cb[(size_t)(row + r) * ldc + col] = f2b(v);
                    } else {  // OMODE 3: z<2 normal (q/k), z==2 transposed (v)
                        if (z < 2)
                            Cb[(size_t)(row + r) * ldc + col] = f2b(v);
                        else
                            Cb[(size_t)by * 65536 + (size_t)col * 128 + rloc + r] = f2b(v);
                    }
                }
            }
        }
    }
}

// ---------------------------------------------------------------------------
// GCN aggregation (bf16 in/out): out[i] = tanh(sum w_e*xw[src] + dinv^2*xw[i] + b)
// one block per node; thread t handles dims 2t, 2t+1; 2-edge unroll for MLP
// ---------------------------------------------------------------------------
__global__ __launch_bounds__(256) void gcn_agg(const unsigned short* __restrict__ xwb,
                                               const float* __restrict__ bias,
                                               const int* __restrict__ off,
                                               const int* __restrict__ src,
                                               const float* __restrict__ wgt,
                                               const float* __restrict__ dinv,
                                               unsigned short* __restrict__ out) {
    const int node = blockIdx.x;
    const int t = threadIdx.x;
    const int d0 = 2 * t;
    const int beg = off[node], end = off[node + 1];
    float a0 = 0.f, a1 = 0.f;
    int e = beg;
    for (; e + 1 < end; e += 2) {
        const int s0 = src[e], s1 = src[e + 1];
        const float w0 = wgt[e], w1 = wgt[e + 1];
        const unsigned u0 = *(const unsigned*)(xwb + (size_t)s0 * DD + d0);
        const unsigned u1 = *(const unsigned*)(xwb + (size_t)s1 * DD + d0);
        a0 += w0 * b2f_lo(u0) + w1 * b2f_lo(u1);
        a1 += w0 * b2f_hi(u0) + w1 * b2f_hi(u1);
    }
    if (e < end) {
        const int s0 = src[e];
        const float w0 = wgt[e];
        const unsigned u0 = *(const unsigned*)(xwb + (size_t)s0 * DD + d0);
        a0 += w0 * b2f_lo(u0);
        a1 += w0 * b2f_hi(u0);
    }
    const float ns = dinv[node] * dinv[node];
    const unsigned un = *(const unsigned*)(xwb + (size_t)node * DD + d0);
    const float r0 = tanhf(a0 + ns * b2f_lo(un) + bias[d0]);
    const float r1 = tanhf(a1 + ns * b2f_hi(un) + bias[d0 + 1]);
    unsigned o = (unsigned)f2b(r0) | ((unsigned)f2b(r1) << 16);
    *(unsigned*)(out + (size_t)node * DD + d0) = o;
}

// ---------------------------------------------------------------------------
// softmax over rows of 128 (fp32 in, bf16 out); one wave per row
// ---------------------------------------------------------------------------
__global__ __launch_bounds__(64) void softmax128(const float* __restrict__ sc,
                                                 unsigned short* __restrict__ p) {
    const int row = blockIdx.x;
    const float* ip = sc + (size_t)row * 128;
    unsigned short* op = p + (size_t)row * 128;
    const int l = threadIdx.x;
    float a = ip[l], b = ip[l + 64];
    float m = fmaxf(a, b);
#pragma unroll
    for (int s = 32; s; s >>= 1) m = fmaxf(m, __shfl_xor(m, s));
    float e0 = expf(a - m), e1 = expf(b - m);
    float sum = e0 + e1;
#pragma unroll
    for (int s = 32; s; s >>= 1) sum += __shfl_xor(sum, s);
    float inv = 1.f / sum;
    op[l] = f2b(e0 * inv);
    op[l + 64] = f2b(e1 * inv);
}

// ---------------------------------------------------------------------------
__global__ __launch_bounds__(128) void pool_fc3(const float* __restrict__ h32,
                                                const float* __restrict__ w3,
                                                const float* __restrict__ b3,
                                                float* __restrict__ util) {
    const int doc = blockIdx.x;
    const int t = threadIdx.x;
    const float* hp = h32 + (size_t)(doc * 128 + t) * 32;
    float s = 0.f;
#pragma unroll
    for (int j = 0; j < 32; ++j) s += hp[j] * w3[j];
    s += b3[0];
    __shared__ float red[128];
    red[t] = s;
    __syncthreads();
    for (int k = 64; k > 0; k >>= 1) {
        if (t < k) red[t] += red[t + k];
        __syncthreads();
    }
    if (t == 0) util[doc] = red[0] * (1.0f / 128.0f);
}

__global__ void final_out(const float* __restrict__ util, const int* __restrict__ ia,
                          const int* __restrict__ ib, float* __restrict__ out) {
    int i = threadIdx.x;
    if (i < NPAIR) {
        float z = util[ib[i]] - util[ia[i]];
        out[i] = 1.f / (1.f + expf(-z));
    }
}

// ---------------------------------------------------------------------------
extern "C" void kernel_launch(void* const* d_in, const int* in_sizes, int n_in,
                              void* d_out, int out_size, void* d_ws, size_t ws_size,
                              hipStream_t stream) {
    const float* x = (const float*)d_in[0];
    const float* w_in = (const float*)d_in[1];
    const float* b_in = (const float*)d_in[2];
    const float* w_mid = (const float*)d_in[3];
    const float* b_mid = (const float*)d_in[4];
    const float* w_out = (const float*)d_in[5];
    const float* b_out = (const float*)d_in[6];
    const float* fc1_w = (const float*)d_in[7];
    const float* fc1_b = (const float*)d_in[8];
    const float* fc2_w = (const float*)d_in[9];
    const float* fc2_b = (const float*)d_in[10];
    const float* fc3_w = (const float*)d_in[11];
    const float* fc3_b = (const float*)d_in[12];
    const float* qkv1_w = (const float*)d_in[13];
    const float* qkv1_b = (const float*)d_in[14];
    const float* qkv2_w = (const float*)d_in[15];
    const float* qkv2_b = (const float*)d_in[16];
    const float* qkv3_w = (const float*)d_in[17];
    const float* qkv3_b = (const float*)d_in[18];
    const int* ei = (const int*)d_in[19];
    const int* idx_a = (const int*)d_in[22];
    const int* idx_b = (const int*)d_in[23];
    float* out = (float*)d_out;

    char* ws = (char*)d_ws;
    const size_t MB = 1024 * 1024;
    const size_t KB = 1024;
    float* dinv = (float*)(ws + 0);
    int* cnt = (int*)(ws + 64 * KB);
    int* off = (int*)(ws + 128 * KB);
    int* pos = (int*)(ws + 192 * KB);
    int* csrc = (int*)(ws + 256 * KB);
    float* cw = (float*)(ws + 768 * KB);
    float* util = (float*)(ws + 1280 * KB);
    unsigned short* xb = (unsigned short*)(ws + 2 * MB);   // 2MB (8192x128)
    float* h32 = (float*)(ws + 2 * MB);                    // alias, live after layers
    unsigned short* wt_in = (unsigned short*)(ws + 4 * MB);                // 128KB
    unsigned short* wt_mid = (unsigned short*)(ws + 4 * MB + 128 * KB);    // 512KB
    unsigned short* wt_out = (unsigned short*)(ws + 4 * MB + 640 * KB);    // 512KB
    unsigned short* wt_fc1 = (unsigned short*)(ws + 4 * MB + 1152 * KB);   // 512KB
    unsigned short* wt_fc2p = (unsigned short*)(ws + 4 * MB + 1664 * KB);  // 128KB padded
    unsigned short* qkv1_t = (unsigned short*)(ws + 6 * MB);   // 3MB (3072x512)
    unsigned short* qkv2_t = (unsigned short*)(ws + 9 * MB);   // 6MB (3x1024x1024)
    unsigned short* qkv3_t = (unsigned short*)(ws + 15 * MB);  // 3MB (3x512x1024)
    unsigned short* h_b = (unsigned short*)(ws + 18 * MB);     // 8MB
    // Region R1 (48MB @26): t1_all; after qkv2: sc/pbf/qb/kbb/vt alias it
    unsigned short* t1_all = (unsigned short*)(ws + 26 * MB);  // 48MB (8192x3072)
    float* sc = (float*)(ws + 26 * MB);                        // 4MB
    unsigned short* pbf = (unsigned short*)(ws + 30 * MB);     // 2MB
    unsigned short* qb = (unsigned short*)(ws + 32 * MB);      // 8MB
    unsigned short* kbb = (unsigned short*)(ws + 40 * MB);     // 8MB (qb+8MB)
    unsigned short* vt = (unsigned short*)(ws + 48 * MB);      // 8MB (qb+16MB)
    // Region R2 (48MB @74): xwb+g_b during GCN; t2_all during qkv; xb2 at end
    unsigned short* xwb = (unsigned short*)(ws + 74 * MB);     // 8MB
    unsigned short* g_b = (unsigned short*)(ws + 82 * MB);     // 8MB
    unsigned short* t2_all = (unsigned short*)(ws + 74 * MB);  // 48MB
    unsigned short* xb2 = (unsigned short*)(ws + 74 * MB);     // 8MB

    // --- weight/activation prep ---
    k_cast<<<NN * F_IN / 1024, 256, 0, stream>>>(x, xb, NN * F_IN);
    hipMemsetAsync(wt_fc2p, 0, 128 * 512 * sizeof(unsigned short), stream);
    dim3 trb(32, 8);
    k_trz<<<dim3(16, 4), trb, 0, stream>>>(w_in, wt_in, F_IN, DD, 0, 0);
    k_trz<<<dim3(16, 16), trb, 0, stream>>>(w_mid, wt_mid, DD, DD, 0, 0);
    k_trz<<<dim3(16, 16), trb, 0, stream>>>(w_out, wt_out, DD, DD, 0, 0);
    k_trz<<<dim3(16, 16), trb, 0, stream>>>(fc1_w, wt_fc1, DD, DD, 0, 0);
    k_trz<<<dim3(1, 16), trb, 0, stream>>>(fc2_w, wt_fc2p, DD, 32, 0, 0);
    k_trz<<<dim3(32, 16, 3), trb, 0, stream>>>(qkv1_w, qkv1_t, DD, HH, 524288, 524288);
    k_trz<<<dim3(32, 32, 3), trb, 0, stream>>>(qkv2_w, qkv2_t, HH, HH, 1048576, 1048576);
    k_trz<<<dim3(16, 32, 3), trb, 0, stream>>>(qkv3_w, qkv3_t, HH, DD, 524288, 524288);

    // --- degree + CSR build ---
    k_zero_cnt<<<NN / 256, 256, 0, stream>>>(cnt);
    k_count<<<EE / 256, 256, 0, stream>>>(ei, cnt);
    k_scan<<<1, 1024, 0, stream>>>(cnt, off, pos, dinv);
    k_fill<<<EE / 256, 256, 0, stream>>>(ei, dinv, pos, csrc, cw);

    auto layer = [&](const unsigned short* hin, const unsigned short* wt,
                     const float* b, int Kin) {
        // GCN: xwb = hin @ w (bf16), aggregate -> g_b (bf16)
        gemm_mfma<0, 1, 1><<<dim3(4, 64), 256, 0, stream>>>(
            hin, wt, nullptr, xwb, Kin, Kin, Kin, 512, 512, 0, 0, 0, 0, 0);
        gcn_agg<<<NN, 256, 0, stream>>>(xwb, b, off, csrc, cw, dinv, g_b);
        // qkv1 (wide M=3072), qkv2 (z=3), qkv3 merged q/k/v (z=3, v transposed)
        gemm_mfma<1, 1, 1><<<dim3(24, 64), 256, 0, stream>>>(
            g_b, qkv1_t, qkv1_b, t1_all, 512, 512, 512, 3072, 3072, 0, 0, 0, 0, 0);
        gemm_mfma<1, 1, 1><<<dim3(8, 64, 3), 256, 0, stream>>>(
            t1_all, qkv2_t, qkv2_b, t2_all, 1024, 3072, 1024, 3072, 1024,
            1024, 1048576, 1024, 1024, 0);
        gemm_mfma<1, 3, 1><<<dim3(4, 64, 3), 256, 0, stream>>>(
            t2_all, qkv3_t, qkv3_b, qb, 1024, 3072, 1024, 512, 512,
            1024, 524288, 4194304, 512, 0);
        // attention: scores (cross-doc via xorb), softmax, AV
        gemm_mfma<3, 0, 0><<<dim3(1, 1, NDOC), 256, 0, stream>>>(
            qb, kbb, nullptr, sc, 512, 512, 512, 128, 128,
            65536, 65536, 16384, 0, 1);
        softmax128<<<NDOC * 128, 64, 0, stream>>>(sc, pbf);
        gemm_mfma<0, 1, 0><<<dim3(4, 1, NDOC), 256, 0, stream>>>(
            pbf, vt, nullptr, h_b, 128, 128, 128, 512, 512,
            16384, 65536, 65536, 0, 1);
    };

    layer(xb, wt_in, b_in, F_IN);
    layer(h_b, wt_mid, b_mid, DD);
    layer(h_b, wt_mid, b_mid, DD);
    layer(h_b, wt_out, b_out, DD);

    // final FCs + pool + pairwise sigmoid
    gemm_mfma<2, 1, 1><<<dim3(4, 64), 256, 0, stream>>>(
        h_b, wt_fc1, fc1_b, xb2, 512, 512, 512, 512, 512, 0, 0, 0, 0, 0);
    gemm_mfma<2, 0, 1><<<dim3(1, 64), 256, 0, stream>>>(
        xb2, wt_fc2p, fc2_b, h32, 512, 512, 512, 32, 32, 0, 0, 0, 0, 0);
    pool_fc3<<<NDOC, 128, 0, stream>>>(h32, fc3_w, fc3_b, util);
    final_out<<<1, 64, 0, stream>>>(util, idx_a, idx_b, out);
}

// Round 6
// 1019.974 us; speedup vs baseline: 1.2660x; 1.2660x over previous
//
#include <hip/hip_runtime.h>
#include <math.h>

#define NN 8192
#define NPD 128
#define F_IN 128
#define DD 512
#define HH 1024
#define EE 131072
#define NDOC 64
#define NPAIR 32

typedef __attribute__((ext_vector_type(8))) short bf16x8;
typedef __attribute__((ext_vector_type(4))) float f32x4;
typedef const __attribute__((address_space(1))) void* gas_ptr;
typedef __attribute__((address_space(3))) void* las_ptr;

__device__ __forceinline__ unsigned short f2b(float f) {
    union { float f; unsigned u; } v; v.f = f;
    unsigned r = v.u + 0x7fffu + ((v.u >> 16) & 1u);
    return (unsigned short)(r >> 16);
}
__device__ __forceinline__ float b2f_lo(unsigned u) {
    union { unsigned u; float f; } v; v.u = u << 16; return v.f;
}
__device__ __forceinline__ float b2f_hi(unsigned u) {
    union { unsigned u; float f; } v; v.u = u & 0xffff0000u; return v.f;
}

// ---------------------------------------------------------------------------
// Degree / CSR construction
// ---------------------------------------------------------------------------
__global__ void k_zero_cnt(int* __restrict__ cnt) {
    int i = blockIdx.x * 256 + threadIdx.x;
    if (i < NN) cnt[i] = 0;
}

__global__ void k_count(const int* __restrict__ ei, int* __restrict__ cnt) {
    int e = blockIdx.x * 256 + threadIdx.x;
    if (e < EE) atomicAdd(&cnt[ei[EE + e]], 1);
}

// exclusive scan of cnt -> off/pos, plus dinv = rsqrt(cnt+1)
__global__ void k_scan(const int* __restrict__ cnt, int* __restrict__ off,
                       int* __restrict__ pos, float* __restrict__ dinv) {
    __shared__ int part[1024];
    int t = threadIdx.x;
    int loc[8];
    int s = 0;
    int base = t * 8;
#pragma unroll
    for (int j = 0; j < 8; ++j) {
        int c = cnt[base + j];
        dinv[base + j] = rsqrtf((float)c + 1.0f);
        loc[j] = s;
        s += c;
    }
    part[t] = s;
    __syncthreads();
    for (int st = 1; st < 1024; st <<= 1) {
        int v = (t >= st) ? part[t - st] : 0;
        __syncthreads();
        part[t] += v;
        __syncthreads();
    }
    int pre = (t > 0) ? part[t - 1] : 0;
#pragma unroll
    for (int j = 0; j < 8; ++j) {
        int val = pre + loc[j];
        off[base + j] = val;
        pos[base + j] = val;
    }
    if (t == 1023) off[NN] = part[1023];
}

__global__ void k_fill(const int* __restrict__ ei, const float* __restrict__ dinv,
                       int* __restrict__ pos, int* __restrict__ csr_src,
                       float* __restrict__ csr_w) {
    int e = blockIdx.x * 256 + threadIdx.x;
    if (e >= EE) return;
    int r = ei[e];
    int c = ei[EE + e];
    int p = atomicAdd(&pos[c], 1);
    csr_src[p] = r;
    csr_w[p] = dinv[r] * dinv[c];
}

// ---------------------------------------------------------------------------
__global__ void k_cast(const float* __restrict__ in, unsigned short* __restrict__ out,
                       int n) {
    int i = (blockIdx.x * 256 + threadIdx.x) * 4;
    if (i < n) {
        float4 v = *(const float4*)(in + i);
        out[i + 0] = f2b(v.x);
        out[i + 1] = f2b(v.y);
        out[i + 2] = f2b(v.z);
        out[i + 3] = f2b(v.w);
    }
}

// transpose W (K x M fp32) -> Wt (M x K bf16), batched over z with strides.
__global__ void k_trz(const float* __restrict__ in, unsigned short* __restrict__ out,
                      int K, int M, long sin, long sout) {
    in += (size_t)blockIdx.z * sin;
    out += (size_t)blockIdx.z * sout;
    __shared__ float t[32][33];
    int bx = blockIdx.x * 32;
    int by = blockIdx.y * 32;
    int tx = threadIdx.x, ty = threadIdx.y;
    for (int i = ty; i < 32; i += 8)
        t[i][tx] = in[(size_t)(by + i) * M + bx + tx];
    __syncthreads();
    for (int i = ty; i < 32; i += 8)
        out[(size_t)(bx + i) * K + by + tx] = f2b(t[tx][i]);
}

// ---------------------------------------------------------------------------
// bf16 MFMA GEMM (generalized): C = act(A @ Bt^T + bias)
// 128x128 tile, BK=64, XOR bank-swizzled LDS layout:
//   LDS[row][seg] holds global 16B-segment (seg ^ (row&7)) of that row.
//   Staged by permuting per-lane global addresses (global_load_lds is
//   lane-contiguous in LDS); read back with seg = c ^ (row&7). All K-loop
//   ds_read_b128 become 2-way-conflict (free) instead of 16-way.
// ACT: 0 none, 1 relu, 2 tanh, 3 scale(1/sqrt(512))
// OMODE: 0 fp32 out, 1 bf16 out, 3 bf16 out but z==2 -> transposed-per-doc
// SWZ: XCD-aware block swizzle (requires gridDim.y % 8 == 0)
// xorb: B z-index = z ^ xorb (cross-doc attention pairing)
// ---------------------------------------------------------------------------
template <int ACT, int OMODE, int SWZ>
__global__ __launch_bounds__(256) void gemm_mfma(
    const unsigned short* __restrict__ A, const unsigned short* __restrict__ Bt,
    const float* __restrict__ bias, void* __restrict__ Cout,
    int K, int lda, int ldbt, int ldc, int mreal,
    long saz, long sbz, long scz, int sbiasz, int xorb) {
    __shared__ unsigned short As[128 * 64];
    __shared__ unsigned short Bs[128 * 64];

    int bx = blockIdx.x, by = blockIdx.y, bz = blockIdx.z;
    if (SWZ) {
        const int nx = gridDim.x, ny = gridDim.y;
        const int band = ny >> 3;
        int b = (bz * ny + by) * nx + bx;
        const int k = b & 7;
        int s = b >> 3;
        bx = s % nx; s /= nx;
        const int yl = s % band; s /= band;
        bz = s;
        by = k * band + yl;
    }
    const int z = bz;
    A += (size_t)z * saz;
    Bt += (size_t)(z ^ xorb) * sbz;
    if (bias) bias += (size_t)z * sbiasz;

    const int tid = threadIdx.x;
    const int wave = tid >> 6, lane = tid & 63;
    const int m0 = by * 128;
    const int n0 = bx * 128;
    const int wm = (wave & 1) * 64, wn = (wave >> 1) * 64;
    const int lhi = lane >> 4;
    const int llo = lane & 15;
    f32x4 acc[4][4] = {};

    // staging with XOR-swizzled per-lane global segment
    const int srow = lane >> 3;                  // 0..7
    const int sseg = (lane & 7) ^ srow;          // swizzled 16B segment
    const unsigned short* ag = A + (size_t)(m0 + wave * 32 + srow) * lda + sseg * 8;
    const unsigned short* bg = Bt + (size_t)(n0 + wave * 32 + srow) * ldbt + sseg * 8;
    unsigned short* al = As + wave * 2048;
    unsigned short* bl = Bs + wave * 2048;

    const int rxor = (llo & 7) * 8;  // read-side XOR key (row&7)*8 shorts

    for (int k0 = 0; k0 < K; k0 += 64) {
#pragma unroll
        for (int r = 0; r < 4; ++r) {
            __builtin_amdgcn_global_load_lds((gas_ptr)(ag + k0 + (size_t)r * 8 * lda),
                                             (las_ptr)(al + r * 512), 16, 0, 0);
            __builtin_amdgcn_global_load_lds((gas_ptr)(bg + k0 + (size_t)r * 8 * ldbt),
                                             (las_ptr)(bl + r * 512), 16, 0, 0);
        }
        __syncthreads();
#pragma unroll
        for (int s = 0; s < 2; ++s) {
            const int cofs = ((s * 4 + lhi) * 8) ^ rxor;  // swizzled col offset
            bf16x8 af[4], bf[4];
#pragma unroll
            for (int i = 0; i < 4; ++i) {
                af[i] = *(const bf16x8*)(As + (wm + i * 16 + llo) * 64 + cofs);
                bf[i] = *(const bf16x8*)(Bs + (wn + i * 16 + llo) * 64 + cofs);
            }
#pragma unroll
            for (int i = 0; i < 4; ++i)
#pragma unroll
                for (int j = 0; j < 4; ++j)
                    acc[i][j] = __builtin_amdgcn_mfma_f32_16x16x32_bf16(af[i], bf[j],
                                                                        acc[i][j], 0, 0, 0);
        }
        __syncthreads();
    }

    float* Cf = (float*)Cout + (size_t)z * scz;
    unsigned short* Cb = (unsigned short*)Cout + (size_t)z * scz;
#pragma unroll
    for (int j = 0; j < 4; ++j) {
        const int col = n0 + wn + j * 16 + llo;
        if (col < mreal) {
            const float bv = bias ? bias[col] : 0.f;
#pragma unroll
            for (int i = 0; i < 4; ++i) {
                const int row = m0 + wm + i * 16 + lhi * 4;
                const int rloc = wm + i * 16 + lhi * 4;
#pragma unroll
                for (int r = 0; r < 4; ++r) {
                    float v = acc[i][j][r] + bv;
                    if (ACT == 1) v = fmaxf(v, 0.f);
                    if (ACT == 2) v = tanhf(v);
                    if (ACT == 3) v *= 0.044194173824159216f;
                    if (OMODE == 0) {
                        Cf[(size_t)(row + r) * ldc + col] = v;
                    } else if (OMODE == 1) {
                        Cb[(size_t)(row + r) * ldc + col] = f2b(v);
                    } else {  // OMODE 3: z<2 normal (q/k), z==2 transposed (v)
                        if (z < 2)
                            Cb[(size_t)(row + r) * ldc + col] = f2b(v);
                        else
                            Cb[(size_t)by * 65536 + (size_t)col * 128 + rloc + r] = f2b(v);
                    }
                }
            }
        }
    }
}

// ---------------------------------------------------------------------------
// GCN aggregation (bf16 in/out)
// ---------------------------------------------------------------------------
__global__ __launch_bounds__(256) void gcn_agg(const unsigned short* __restrict__ xwb,
                                               const float* __restrict__ bias,
                                               const int* __restrict__ off,
                                               const int* __restrict__ src,
                                               const float* __restrict__ wgt,
                                               const float* __restrict__ dinv,
                                               unsigned short* __restrict__ out) {
    const int node = blockIdx.x;
    const int t = threadIdx.x;
    const int d0 = 2 * t;
    const int beg = off[node], end = off[node + 1];
    float a0 = 0.f, a1 = 0.f;
    int e = beg;
    for (; e + 1 < end; e += 2) {
        const int s0 = src[e], s1 = src[e + 1];
        const float w0 = wgt[e], w1 = wgt[e + 1];
        const unsigned u0 = *(const unsigned*)(xwb + (size_t)s0 * DD + d0);
        const unsigned u1 = *(const unsigned*)(xwb + (size_t)s1 * DD + d0);
        a0 += w0 * b2f_lo(u0) + w1 * b2f_lo(u1);
        a1 += w0 * b2f_hi(u0) + w1 * b2f_hi(u1);
    }
    if (e < end) {
        const int s0 = src[e];
        const float w0 = wgt[e];
        const unsigned u0 = *(const unsigned*)(xwb + (size_t)s0 * DD + d0);
        a0 += w0 * b2f_lo(u0);
        a1 += w0 * b2f_hi(u0);
    }
    const float ns = dinv[node] * dinv[node];
    const unsigned un = *(const unsigned*)(xwb + (size_t)node * DD + d0);
    const float r0 = tanhf(a0 + ns * b2f_lo(un) + bias[d0]);
    const float r1 = tanhf(a1 + ns * b2f_hi(un) + bias[d0 + 1]);
    unsigned o = (unsigned)f2b(r0) | ((unsigned)f2b(r1) << 16);
    *(unsigned*)(out + (size_t)node * DD + d0) = o;
}

// ---------------------------------------------------------------------------
// softmax over rows of 128 (fp32 in, bf16 out); one wave per row
// ---------------------------------------------------------------------------
__global__ __launch_bounds__(64) void softmax128(const float* __restrict__ sc,
                                                 unsigned short* __restrict__ p) {
    const int row = blockIdx.x;
    const float* ip = sc + (size_t)row * 128;
    unsigned short* op = p + (size_t)row * 128;
    const int l = threadIdx.x;
    float a = ip[l], b = ip[l + 64];
    float m = fmaxf(a, b);
#pragma unroll
    for (int s = 32; s; s >>= 1) m = fmaxf(m, __shfl_xor(m, s));
    float e0 = expf(a - m), e1 = expf(b - m);
    float sum = e0 + e1;
#pragma unroll
    for (int s = 32; s; s >>= 1) sum += __shfl_xor(sum, s);
    float inv = 1.f / sum;
    op[l] = f2b(e0 * inv);
    op[l + 64] = f2b(e1 * inv);
}

// ---------------------------------------------------------------------------
__global__ __launch_bounds__(128) void pool_fc3(const float* __restrict__ h32,
                                                const float* __restrict__ w3,
                                                const float* __restrict__ b3,
                                                float* __restrict__ util) {
    const int doc = blockIdx.x;
    const int t = threadIdx.x;
    const float* hp = h32 + (size_t)(doc * 128 + t) * 32;
    float s = 0.f;
#pragma unroll
    for (int j = 0; j < 32; ++j) s += hp[j] * w3[j];
    s += b3[0];
    __shared__ float red[128];
    red[t] = s;
    __syncthreads();
    for (int k = 64; k > 0; k >>= 1) {
        if (t < k) red[t] += red[t + k];
        __syncthreads();
    }
    if (t == 0) util[doc] = red[0] * (1.0f / 128.0f);
}

__global__ void final_out(const float* __restrict__ util, const int* __restrict__ ia,
                          const int* __restrict__ ib, float* __restrict__ out) {
    int i = threadIdx.x;
    if (i < NPAIR) {
        float z = util[ib[i]] - util[ia[i]];
        out[i] = 1.f / (1.f + expf(-z));
    }
}

// ---------------------------------------------------------------------------
extern "C" void kernel_launch(void* const* d_in, const int* in_sizes, int n_in,
                              void* d_out, int out_size, void* d_ws, size_t ws_size,
                              hipStream_t stream) {
    const float* x = (const float*)d_in[0];
    const float* w_in = (const float*)d_in[1];
    const float* b_in = (const float*)d_in[2];
    const float* w_mid = (const float*)d_in[3];
    const float* b_mid = (const float*)d_in[4];
    const float* w_out = (const float*)d_in[5];
    const float* b_out = (const float*)d_in[6];
    const float* fc1_w = (const float*)d_in[7];
    const float* fc1_b = (const float*)d_in[8];
    const float* fc2_w = (const float*)d_in[9];
    const float* fc2_b = (const float*)d_in[10];
    const float* fc3_w = (const float*)d_in[11];
    const float* fc3_b = (const float*)d_in[12];
    const float* qkv1_w = (const float*)d_in[13];
    const float* qkv1_b = (const float*)d_in[14];
    const float* qkv2_w = (const float*)d_in[15];
    const float* qkv2_b = (const float*)d_in[16];
    const float* qkv3_w = (const float*)d_in[17];
    const float* qkv3_b = (const float*)d_in[18];
    const int* ei = (const int*)d_in[19];
    const int* idx_a = (const int*)d_in[22];
    const int* idx_b = (const int*)d_in[23];
    float* out = (float*)d_out;

    char* ws = (char*)d_ws;
    const size_t MB = 1024 * 1024;
    const size_t KB = 1024;
    float* dinv = (float*)(ws + 0);
    int* cnt = (int*)(ws + 64 * KB);
    int* off = (int*)(ws + 128 * KB);
    int* pos = (int*)(ws + 192 * KB);
    int* csrc = (int*)(ws + 256 * KB);
    float* cw = (float*)(ws + 768 * KB);
    float* util = (float*)(ws + 1280 * KB);
    unsigned short* xb = (unsigned short*)(ws + 2 * MB);   // 2MB (8192x128)
    float* h32 = (float*)(ws + 2 * MB);                    // alias, live after layers
    unsigned short* wt_in = (unsigned short*)(ws + 4 * MB);                // 128KB
    unsigned short* wt_mid = (unsigned short*)(ws + 4 * MB + 128 * KB);    // 512KB
    unsigned short* wt_out = (unsigned short*)(ws + 4 * MB + 640 * KB);    // 512KB
    unsigned short* wt_fc1 = (unsigned short*)(ws + 4 * MB + 1152 * KB);   // 512KB
    unsigned short* wt_fc2p = (unsigned short*)(ws + 4 * MB + 1664 * KB);  // 128KB padded
    unsigned short* qkv1_t = (unsigned short*)(ws + 6 * MB);   // 3MB (3072x512)
    unsigned short* qkv2_t = (unsigned short*)(ws + 9 * MB);   // 6MB (3x1024x1024)
    unsigned short* qkv3_t = (unsigned short*)(ws + 15 * MB);  // 3MB (3x512x1024)
    unsigned short* h_b = (unsigned short*)(ws + 18 * MB);     // 8MB
    // Region R1 (48MB @26): t1_all; after qkv2: sc/pbf/qb/kbb/vt alias it
    unsigned short* t1_all = (unsigned short*)(ws + 26 * MB);  // 48MB (8192x3072)
    float* sc = (float*)(ws + 26 * MB);                        // 4MB
    unsigned short* pbf = (unsigned short*)(ws + 30 * MB);     // 2MB
    unsigned short* qb = (unsigned short*)(ws + 32 * MB);      // 8MB
    unsigned short* kbb = (unsigned short*)(ws + 40 * MB);     // 8MB (qb+8MB)
    unsigned short* vt = (unsigned short*)(ws + 48 * MB);      // 8MB (qb+16MB)
    // Region R2 (48MB @74): xwb+g_b during GCN; t2_all during qkv; xb2 at end
    unsigned short* xwb = (unsigned short*)(ws + 74 * MB);     // 8MB
    unsigned short* g_b = (unsigned short*)(ws + 82 * MB);     // 8MB
    unsigned short* t2_all = (unsigned short*)(ws + 74 * MB);  // 48MB
    unsigned short* xb2 = (unsigned short*)(ws + 74 * MB);     // 8MB

    // --- weight/activation prep ---
    k_cast<<<NN * F_IN / 1024, 256, 0, stream>>>(x, xb, NN * F_IN);
    hipMemsetAsync(wt_fc2p, 0, 128 * 512 * sizeof(unsigned short), stream);
    dim3 trb(32, 8);
    k_trz<<<dim3(16, 4), trb, 0, stream>>>(w_in, wt_in, F_IN, DD, 0, 0);
    k_trz<<<dim3(16, 16), trb, 0, stream>>>(w_mid, wt_mid, DD, DD, 0, 0);
    k_trz<<<dim3(16, 16), trb, 0, stream>>>(w_out, wt_out, DD, DD, 0, 0);
    k_trz<<<dim3(16, 16), trb, 0, stream>>>(fc1_w, wt_fc1, DD, DD, 0, 0);
    k_trz<<<dim3(1, 16), trb, 0, stream>>>(fc2_w, wt_fc2p, DD, 32, 0, 0);
    k_trz<<<dim3(32, 16, 3), trb, 0, stream>>>(qkv1_w, qkv1_t, DD, HH, 524288, 524288);
    k_trz<<<dim3(32, 32, 3), trb, 0, stream>>>(qkv2_w, qkv2_t, HH, HH, 1048576, 1048576);
    k_trz<<<dim3(16, 32, 3), trb, 0, stream>>>(qkv3_w, qkv3_t, HH, DD, 524288, 524288);

    // --- degree + CSR build ---
    k_zero_cnt<<<NN / 256, 256, 0, stream>>>(cnt);
    k_count<<<EE / 256, 256, 0, stream>>>(ei, cnt);
    k_scan<<<1, 1024, 0, stream>>>(cnt, off, pos, dinv);
    k_fill<<<EE / 256, 256, 0, stream>>>(ei, dinv, pos, csrc, cw);

    auto layer = [&](const unsigned short* hin, const unsigned short* wt,
                     const float* b, int Kin) {
        // GCN: xwb = hin @ w (bf16), aggregate -> g_b (bf16)
        gemm_mfma<0, 1, 1><<<dim3(4, 64), 256, 0, stream>>>(
            hin, wt, nullptr, xwb, Kin, Kin, Kin, 512, 512, 0, 0, 0, 0, 0);
        gcn_agg<<<NN, 256, 0, stream>>>(xwb, b, off, csrc, cw, dinv, g_b);
        // qkv1 (wide M=3072), qkv2 (z=3), qkv3 merged q/k/v (z=3, v transposed)
        gemm_mfma<1, 1, 1><<<dim3(24, 64), 256, 0, stream>>>(
            g_b, qkv1_t, qkv1_b, t1_all, 512, 512, 512, 3072, 3072, 0, 0, 0, 0, 0);
        gemm_mfma<1, 1, 1><<<dim3(8, 64, 3), 256, 0, stream>>>(
            t1_all, qkv2_t, qkv2_b, t2_all, 1024, 3072, 1024, 3072, 1024,
            1024, 1048576, 1024, 1024, 0);
        gemm_mfma<1, 3, 1><<<dim3(4, 64, 3), 256, 0, stream>>>(
            t2_all, qkv3_t, qkv3_b, qb, 1024, 3072, 1024, 512, 512,
            1024, 524288, 4194304, 512, 0);
        // attention: scores (cross-doc via xorb), softmax, AV
        gemm_mfma<3, 0, 0><<<dim3(1, 1, NDOC), 256, 0, stream>>>(
            qb, kbb, nullptr, sc, 512, 512, 512, 128, 128,
            65536, 65536, 16384, 0, 1);
        softmax128<<<NDOC * 128, 64, 0, stream>>>(sc, pbf);
        gemm_mfma<0, 1, 0><<<dim3(4, 1, NDOC), 256, 0, stream>>>(
            pbf, vt, nullptr, h_b, 128, 128, 128, 512, 512,
            16384, 65536, 65536, 0, 1);
    };

    layer(xb, wt_in, b_in, F_IN);
    layer(h_b, wt_mid, b_mid, DD);
    layer(h_b, wt_mid, b_mid, DD);
    layer(h_b, wt_out, b_out, DD);

    // final FCs + pool + pairwise sigmoid
    gemm_mfma<2, 1, 1><<<dim3(4, 64), 256, 0, stream>>>(
        h_b, wt_fc1, fc1_b, xb2, 512, 512, 512, 512, 512, 0, 0, 0, 0, 0);
    gemm_mfma<2, 0, 1><<<dim3(1, 64), 256, 0, stream>>>(
        xb2, wt_fc2p, fc2_b, h32, 512, 512, 512, 32, 32, 0, 0, 0, 0, 0);
    pool_fc3<<<NDOC, 128, 0, stream>>>(h32, fc3_w, fc3_b, util);
    final_out<<<1, 64, 0, stream>>>(util, idx_a, idx_b, out);
}

// Round 7
// 1012.215 us; speedup vs baseline: 1.2757x; 1.0077x over previous
//
#include <hip/hip_runtime.h>
#include <math.h>

#define NN 8192
#define NPD 128
#define F_IN 128
#define DD 512
#define HH 1024
#define EE 131072
#define NDOC 64
#define NPAIR 32

typedef __attribute__((ext_vector_type(8))) short bf16x8;
typedef __attribute__((ext_vector_type(4))) float f32x4;
typedef const __attribute__((address_space(1))) void* gas_ptr;
typedef __attribute__((address_space(3))) void* las_ptr;

__device__ __forceinline__ unsigned short f2b(float f) {
    union { float f; unsigned u; } v; v.f = f;
    unsigned r = v.u + 0x7fffu + ((v.u >> 16) & 1u);
    return (unsigned short)(r >> 16);
}
__device__ __forceinline__ float b2f_lo(unsigned u) {
    union { unsigned u; float f; } v; v.u = u << 16; return v.f;
}
__device__ __forceinline__ float b2f_hi(unsigned u) {
    union { unsigned u; float f; } v; v.u = u & 0xffff0000u; return v.f;
}
__device__ __forceinline__ unsigned char f2fp8(float f) {
    return (unsigned char)(__builtin_amdgcn_cvt_pk_fp8_f32(f, f, 0, false) & 0xff);
}

// ---------------------------------------------------------------------------
// Degree / CSR construction
// ---------------------------------------------------------------------------
__global__ void k_zero_cnt(int* __restrict__ cnt) {
    int i = blockIdx.x * 256 + threadIdx.x;
    if (i < NN) cnt[i] = 0;
}

__global__ void k_count(const int* __restrict__ ei, int* __restrict__ cnt) {
    int e = blockIdx.x * 256 + threadIdx.x;
    if (e < EE) atomicAdd(&cnt[ei[EE + e]], 1);
}

__global__ void k_scan(const int* __restrict__ cnt, int* __restrict__ off,
                       int* __restrict__ pos, float* __restrict__ dinv) {
    __shared__ int part[1024];
    int t = threadIdx.x;
    int loc[8];
    int s = 0;
    int base = t * 8;
#pragma unroll
    for (int j = 0; j < 8; ++j) {
        int c = cnt[base + j];
        dinv[base + j] = rsqrtf((float)c + 1.0f);
        loc[j] = s;
        s += c;
    }
    part[t] = s;
    __syncthreads();
    for (int st = 1; st < 1024; st <<= 1) {
        int v = (t >= st) ? part[t - st] : 0;
        __syncthreads();
        part[t] += v;
        __syncthreads();
    }
    int pre = (t > 0) ? part[t - 1] : 0;
#pragma unroll
    for (int j = 0; j < 8; ++j) {
        int val = pre + loc[j];
        off[base + j] = val;
        pos[base + j] = val;
    }
    if (t == 1023) off[NN] = part[1023];
}

__global__ void k_fill(const int* __restrict__ ei, const float* __restrict__ dinv,
                       int* __restrict__ pos, int* __restrict__ csr_src,
                       float* __restrict__ csr_w) {
    int e = blockIdx.x * 256 + threadIdx.x;
    if (e >= EE) return;
    int r = ei[e];
    int c = ei[EE + e];
    int p = atomicAdd(&pos[c], 1);
    csr_src[p] = r;
    csr_w[p] = dinv[r] * dinv[c];
}

// ---------------------------------------------------------------------------
__global__ void k_cast(const float* __restrict__ in, unsigned short* __restrict__ out,
                       int n) {
    int i = (blockIdx.x * 256 + threadIdx.x) * 4;
    if (i < n) {
        float4 v = *(const float4*)(in + i);
        out[i + 0] = f2b(v.x);
        out[i + 1] = f2b(v.y);
        out[i + 2] = f2b(v.z);
        out[i + 3] = f2b(v.w);
    }
}

// transpose W (K x M fp32) -> Wt (M x K), batched over z. F8: fp8 out else bf16.
template <int F8>
__global__ void k_trz(const float* __restrict__ in, void* __restrict__ outv,
                      int K, int M, long sin, long sout) {
    in += (size_t)blockIdx.z * sin;
    __shared__ float t[32][33];
    int bx = blockIdx.x * 32;
    int by = blockIdx.y * 32;
    int tx = threadIdx.x, ty = threadIdx.y;
    for (int i = ty; i < 32; i += 8)
        t[i][tx] = in[(size_t)(by + i) * M + bx + tx];
    __syncthreads();
    if (F8) {
        unsigned char* out = (unsigned char*)outv + (size_t)blockIdx.z * sout;
        for (int i = ty; i < 32; i += 8)
            out[(size_t)(bx + i) * K + by + tx] = f2fp8(t[tx][i]);
    } else {
        unsigned short* out = (unsigned short*)outv + (size_t)blockIdx.z * sout;
        for (int i = ty; i < 32; i += 8)
            out[(size_t)(bx + i) * K + by + tx] = f2b(t[tx][i]);
    }
}

// ---------------------------------------------------------------------------
// bf16 MFMA GEMM: C = act(A @ Bt^T + bias). 128x128 tile, BK=64,
// XOR bank-swizzled LDS. ACT: 0 none,1 relu,2 tanh,3 scale(1/sqrt512)
// OMODE: 0 fp32, 1 bf16, 3 bf16 but z==2 -> transposed-per-doc (vt)
// ---------------------------------------------------------------------------
template <int ACT, int OMODE, int SWZ>
__global__ __launch_bounds__(256) void gemm_mfma(
    const unsigned short* __restrict__ A, const unsigned short* __restrict__ Bt,
    const float* __restrict__ bias, void* __restrict__ Cout,
    int K, int lda, int ldbt, int ldc, int mreal,
    long saz, long sbz, long scz, int sbiasz, int xorb) {
    __shared__ unsigned short As[128 * 64];
    __shared__ unsigned short Bs[128 * 64];

    int bx = blockIdx.x, by = blockIdx.y, bz = blockIdx.z;
    if (SWZ) {
        const int nx = gridDim.x, ny = gridDim.y;
        const int band = ny >> 3;
        int b = (bz * ny + by) * nx + bx;
        const int k = b & 7;
        int s = b >> 3;
        bx = s % nx; s /= nx;
        const int yl = s % band; s /= band;
        bz = s;
        by = k * band + yl;
    }
    const int z = bz;
    A += (size_t)z * saz;
    Bt += (size_t)(z ^ xorb) * sbz;
    if (bias) bias += (size_t)z * sbiasz;

    const int tid = threadIdx.x;
    const int wave = tid >> 6, lane = tid & 63;
    const int m0 = by * 128;
    const int n0 = bx * 128;
    const int wm = (wave & 1) * 64, wn = (wave >> 1) * 64;
    const int lhi = lane >> 4;
    const int llo = lane & 15;
    f32x4 acc[4][4] = {};

    const int srow = lane >> 3;
    const int sseg = (lane & 7) ^ srow;
    const unsigned short* ag = A + (size_t)(m0 + wave * 32 + srow) * lda + sseg * 8;
    const unsigned short* bg = Bt + (size_t)(n0 + wave * 32 + srow) * ldbt + sseg * 8;
    unsigned short* al = As + wave * 2048;
    unsigned short* bl = Bs + wave * 2048;

    const int rxor = (llo & 7) * 8;

    for (int k0 = 0; k0 < K; k0 += 64) {
#pragma unroll
        for (int r = 0; r < 4; ++r) {
            __builtin_amdgcn_global_load_lds((gas_ptr)(ag + k0 + (size_t)r * 8 * lda),
                                             (las_ptr)(al + r * 512), 16, 0, 0);
            __builtin_amdgcn_global_load_lds((gas_ptr)(bg + k0 + (size_t)r * 8 * ldbt),
                                             (las_ptr)(bl + r * 512), 16, 0, 0);
        }
        __syncthreads();
#pragma unroll
        for (int s = 0; s < 2; ++s) {
            const int cofs = ((s * 4 + lhi) * 8) ^ rxor;
            bf16x8 af[4], bf[4];
#pragma unroll
            for (int i = 0; i < 4; ++i) {
                af[i] = *(const bf16x8*)(As + (wm + i * 16 + llo) * 64 + cofs);
                bf[i] = *(const bf16x8*)(Bs + (wn + i * 16 + llo) * 64 + cofs);
            }
#pragma unroll
            for (int i = 0; i < 4; ++i)
#pragma unroll
                for (int j = 0; j < 4; ++j)
                    acc[i][j] = __builtin_amdgcn_mfma_f32_16x16x32_bf16(af[i], bf[j],
                                                                        acc[i][j], 0, 0, 0);
        }
        __syncthreads();
    }

    float* Cf = (float*)Cout + (size_t)z * scz;
    unsigned short* Cb = (unsigned short*)Cout + (size_t)z * scz;
#pragma unroll
    for (int j = 0; j < 4; ++j) {
        const int col = n0 + wn + j * 16 + llo;
        if (col < mreal) {
            const float bv = bias ? bias[col] : 0.f;
#pragma unroll
            for (int i = 0; i < 4; ++i) {
                const int row = m0 + wm + i * 16 + lhi * 4;
                const int rloc = wm + i * 16 + lhi * 4;
#pragma unroll
                for (int r = 0; r < 4; ++r) {
                    float v = acc[i][j][r] + bv;
                    if (ACT == 1) v = fmaxf(v, 0.f);
                    if (ACT == 2) v = tanhf(v);
                    if (ACT == 3) v *= 0.044194173824159216f;
                    if (OMODE == 0) {
                        Cf[(size_t)(row + r) * ldc + col] = v;
                    } else if (OMODE == 1) {
                        Cb[(size_t)(row + r) * ldc + col] = f2b(v);
                    } else {
                        if (z < 2)
                            Cb[(size_t)(row + r) * ldc + col] = f2b(v);
                        else
                            Cb[(size_t)by * 65536 + (size_t)col * 128 + rloc + r] = f2b(v);
                    }
                }
            }
        }
    }
}

// ---------------------------------------------------------------------------
// fp8 e4m3 MFMA GEMM: C = act(A @ Bt^T + bias). A,Bt fp8 (byte) K-contig.
// 128x128 tile, BK=128 (same 32KB LDS, half the barriers of bf16 BK=64),
// XOR bank-swizzled (8 segs of 16B per 128B row; reads are b64, 2-way free).
// ACT: 1 relu. OMODE: 10 fp8 out, 3 bf16 out with z==2 -> vt transpose.
// ---------------------------------------------------------------------------
template <int ACT, int OMODE, int SWZ>
__global__ __launch_bounds__(256) void gemm_f8(
    const unsigned char* __restrict__ A, const unsigned char* __restrict__ Bt,
    const float* __restrict__ bias, void* __restrict__ Cout,
    int K, int lda, int ldbt, int ldc, int mreal,
    long saz, long sbz, long scz, int sbiasz) {
    __shared__ unsigned char As[128 * 128];
    __shared__ unsigned char Bs[128 * 128];

    int bx = blockIdx.x, by = blockIdx.y, bz = blockIdx.z;
    if (SWZ) {
        const int nx = gridDim.x, ny = gridDim.y;
        const int band = ny >> 3;
        int b = (bz * ny + by) * nx + bx;
        const int k = b & 7;
        int s = b >> 3;
        bx = s % nx; s /= nx;
        const int yl = s % band; s /= band;
        bz = s;
        by = k * band + yl;
    }
    const int z = bz;
    A += (size_t)z * saz;
    Bt += (size_t)z * sbz;
    if (bias) bias += (size_t)z * sbiasz;

    const int tid = threadIdx.x;
    const int wave = tid >> 6, lane = tid & 63;
    const int m0 = by * 128;
    const int n0 = bx * 128;
    const int wm = (wave & 1) * 64, wn = (wave >> 1) * 64;
    const int lhi = lane >> 4;
    const int llo = lane & 15;
    f32x4 acc[4][4] = {};

    // staging: 8 rows x 8 16B-segments per instruction; XOR-swizzled segment
    const int srow = lane >> 3;
    const int sseg = (lane & 7) ^ srow;
    const unsigned char* ag = A + (size_t)(m0 + wave * 32 + srow) * lda + sseg * 16;
    const unsigned char* bg = Bt + (size_t)(n0 + wave * 32 + srow) * ldbt + sseg * 16;
    unsigned char* al = As + wave * 4096;
    unsigned char* bl = Bs + wave * 4096;

    const int rxor = llo & 7;  // seg-XOR key = row&7

    for (int k0 = 0; k0 < K; k0 += 128) {
#pragma unroll
        for (int r = 0; r < 4; ++r) {
            __builtin_amdgcn_global_load_lds((gas_ptr)(ag + k0 + (size_t)r * 8 * lda),
                                             (las_ptr)(al + r * 1024), 16, 0, 0);
            __builtin_amdgcn_global_load_lds((gas_ptr)(bg + k0 + (size_t)r * 8 * ldbt),
                                             (las_ptr)(bl + r * 1024), 16, 0, 0);
        }
        __syncthreads();
#pragma unroll
        for (int s = 0; s < 4; ++s) {
            // lane's 8 fp8 at k-bytes s*32 + lhi*8 -> swizzled seg + half
            const int cofs = (((s * 2 + (lhi >> 1)) ^ rxor) << 4) + ((lhi & 1) << 3);
            long af[4], bf[4];
#pragma unroll
            for (int i = 0; i < 4; ++i) {
                af[i] = *(const long*)(As + (wm + i * 16 + llo) * 128 + cofs);
                bf[i] = *(const long*)(Bs + (wn + i * 16 + llo) * 128 + cofs);
            }
#pragma unroll
            for (int i = 0; i < 4; ++i)
#pragma unroll
                for (int j = 0; j < 4; ++j)
                    acc[i][j] = __builtin_amdgcn_mfma_f32_16x16x32_fp8_fp8(
                        af[i], bf[j], acc[i][j], 0, 0, 0);
        }
        __syncthreads();
    }

    unsigned char* C8 = (unsigned char*)Cout + (size_t)z * scz;
    unsigned short* Cb = (unsigned short*)Cout + (size_t)z * scz;
#pragma unroll
    for (int j = 0; j < 4; ++j) {
        const int col = n0 + wn + j * 16 + llo;
        if (col < mreal) {
            const float bv = bias ? bias[col] : 0.f;
#pragma unroll
            for (int i = 0; i < 4; ++i) {
                const int row = m0 + wm + i * 16 + lhi * 4;
                const int rloc = wm + i * 16 + lhi * 4;
#pragma unroll
                for (int r = 0; r < 4; ++r) {
                    float v = acc[i][j][r] + bv;
                    if (ACT == 1) v = fmaxf(v, 0.f);
                    if (OMODE == 10) {
                        C8[(size_t)(row + r) * ldc + col] = f2fp8(v);
                    } else {  // OMODE 3: bf16; z==2 -> vt transpose
                        if (z < 2)
                            Cb[(size_t)(row + r) * ldc + col] = f2b(v);
                        else
                            Cb[(size_t)by * 65536 + (size_t)col * 128 + rloc + r] = f2b(v);
                    }
                }
            }
        }
    }
}

// ---------------------------------------------------------------------------
// GCN aggregation (bf16 in, fp8 out): out = tanh(sum w*xw[src] + dinv^2*xw + b)
// ---------------------------------------------------------------------------
__global__ __launch_bounds__(256) void gcn_agg(const unsigned short* __restrict__ xwb,
                                               const float* __restrict__ bias,
                                               const int* __restrict__ off,
                                               const int* __restrict__ src,
                                               const float* __restrict__ wgt,
                                               const float* __restrict__ dinv,
                                               unsigned char* __restrict__ out) {
    const int node = blockIdx.x;
    const int t = threadIdx.x;
    const int d0 = 2 * t;
    const int beg = off[node], end = off[node + 1];
    float a0 = 0.f, a1 = 0.f;
    int e = beg;
    for (; e + 1 < end; e += 2) {
        const int s0 = src[e], s1 = src[e + 1];
        const float w0 = wgt[e], w1 = wgt[e + 1];
        const unsigned u0 = *(const unsigned*)(xwb + (size_t)s0 * DD + d0);
        const unsigned u1 = *(const unsigned*)(xwb + (size_t)s1 * DD + d0);
        a0 += w0 * b2f_lo(u0) + w1 * b2f_lo(u1);
        a1 += w0 * b2f_hi(u0) + w1 * b2f_hi(u1);
    }
    if (e < end) {
        const int s0 = src[e];
        const float w0 = wgt[e];
        const unsigned u0 = *(const unsigned*)(xwb + (size_t)s0 * DD + d0);
        a0 += w0 * b2f_lo(u0);
        a1 += w0 * b2f_hi(u0);
    }
    const float ns = dinv[node] * dinv[node];
    const unsigned un = *(const unsigned*)(xwb + (size_t)node * DD + d0);
    const float r0 = tanhf(a0 + ns * b2f_lo(un) + bias[d0]);
    const float r1 = tanhf(a1 + ns * b2f_hi(un) + bias[d0 + 1]);
    unsigned p = (unsigned)__builtin_amdgcn_cvt_pk_fp8_f32(r0, r1, 0, false);
    *(unsigned short*)(out + (size_t)node * DD + d0) = (unsigned short)(p & 0xffff);
}

// ---------------------------------------------------------------------------
__global__ __launch_bounds__(64) void softmax128(const float* __restrict__ sc,
                                                 unsigned short* __restrict__ p) {
    const int row = blockIdx.x;
    const float* ip = sc + (size_t)row * 128;
    unsigned short* op = p + (size_t)row * 128;
    const int l = threadIdx.x;
    float a = ip[l], b = ip[l + 64];
    float m = fmaxf(a, b);
#pragma unroll
    for (int s = 32; s; s >>= 1) m = fmaxf(m, __shfl_xor(m, s));
    float e0 = expf(a - m), e1 = expf(b - m);
    float sum = e0 + e1;
#pragma unroll
    for (int s = 32; s; s >>= 1) sum += __shfl_xor(sum, s);
    float inv = 1.f / sum;
    op[l] = f2b(e0 * inv);
    op[l + 64] = f2b(e1 * inv);
}

// ---------------------------------------------------------------------------
__global__ __launch_bounds__(128) void pool_fc3(const float* __restrict__ h32,
                                                const float* __restrict__ w3,
                                                const float* __restrict__ b3,
                                                float* __restrict__ util) {
    const int doc = blockIdx.x;
    const int t = threadIdx.x;
    const float* hp = h32 + (size_t)(doc * 128 + t) * 32;
    float s = 0.f;
#pragma unroll
    for (int j = 0; j < 32; ++j) s += hp[j] * w3[j];
    s += b3[0];
    __shared__ float red[128];
    red[t] = s;
    __syncthreads();
    for (int k = 64; k > 0; k >>= 1) {
        if (t < k) red[t] += red[t + k];
        __syncthreads();
    }
    if (t == 0) util[doc] = red[0] * (1.0f / 128.0f);
}

__global__ void final_out(const float* __restrict__ util, const int* __restrict__ ia,
                          const int* __restrict__ ib, float* __restrict__ out) {
    int i = threadIdx.x;
    if (i < NPAIR) {
        float z = util[ib[i]] - util[ia[i]];
        out[i] = 1.f / (1.f + expf(-z));
    }
}

// ---------------------------------------------------------------------------
extern "C" void kernel_launch(void* const* d_in, const int* in_sizes, int n_in,
                              void* d_out, int out_size, void* d_ws, size_t ws_size,
                              hipStream_t stream) {
    const float* x = (const float*)d_in[0];
    const float* w_in = (const float*)d_in[1];
    const float* b_in = (const float*)d_in[2];
    const float* w_mid = (const float*)d_in[3];
    const float* b_mid = (const float*)d_in[4];
    const float* w_out = (const float*)d_in[5];
    const float* b_out = (const float*)d_in[6];
    const float* fc1_w = (const float*)d_in[7];
    const float* fc1_b = (const float*)d_in[8];
    const float* fc2_w = (const float*)d_in[9];
    const float* fc2_b = (const float*)d_in[10];
    const float* fc3_w = (const float*)d_in[11];
    const float* fc3_b = (const float*)d_in[12];
    const float* qkv1_w = (const float*)d_in[13];
    const float* qkv1_b = (const float*)d_in[14];
    const float* qkv2_w = (const float*)d_in[15];
    const float* qkv2_b = (const float*)d_in[16];
    const float* qkv3_w = (const float*)d_in[17];
    const float* qkv3_b = (const float*)d_in[18];
    const int* ei = (const int*)d_in[19];
    const int* idx_a = (const int*)d_in[22];
    const int* idx_b = (const int*)d_in[23];
    float* out = (float*)d_out;

    char* ws = (char*)d_ws;
    const size_t MB = 1024 * 1024;
    const size_t KB = 1024;
    float* dinv = (float*)(ws + 0);
    int* cnt = (int*)(ws + 64 * KB);
    int* off = (int*)(ws + 128 * KB);
    int* pos = (int*)(ws + 192 * KB);
    int* csrc = (int*)(ws + 256 * KB);
    float* cw = (float*)(ws + 768 * KB);
    float* util = (float*)(ws + 1280 * KB);
    unsigned short* xb = (unsigned short*)(ws + 2 * MB);   // 2MB (8192x128 bf16)
    float* h32 = (float*)(ws + 2 * MB);                    // alias, live after layers
    unsigned short* wt_in = (unsigned short*)(ws + 4 * MB);                // 128KB
    unsigned short* wt_mid = (unsigned short*)(ws + 4 * MB + 128 * KB);    // 512KB
    unsigned short* wt_out = (unsigned short*)(ws + 4 * MB + 640 * KB);    // 512KB
    unsigned short* wt_fc1 = (unsigned short*)(ws + 4 * MB + 1152 * KB);   // 512KB
    unsigned short* wt_fc2p = (unsigned short*)(ws + 4 * MB + 1664 * KB);  // 128KB
    unsigned char* qkv1_8 = (unsigned char*)(ws + 6 * MB);   // 1.5MB (3072x512)
    unsigned char* qkv2_8 = (unsigned char*)(ws + 8 * MB);   // 3MB (3x1024x1024)
    unsigned char* qkv3_8 = (unsigned char*)(ws + 11 * MB);  // 1.5MB (3x512x1024)
    unsigned short* h_b = (unsigned short*)(ws + 13 * MB);   // 8MB bf16
    unsigned char* g8 = (unsigned char*)(ws + 21 * MB);      // 4MB fp8 (8192x512)
    unsigned char* t1_8 = (unsigned char*)(ws + 25 * MB);    // 24MB (8192x3072)
    unsigned char* t2_8 = (unsigned char*)(ws + 49 * MB);    // 24MB
    unsigned short* xwb = (unsigned short*)(ws + 73 * MB);   // 8MB bf16
    unsigned short* qb = (unsigned short*)(ws + 81 * MB);    // 8MB
    unsigned short* kbb = (unsigned short*)(ws + 89 * MB);   // 8MB (qb + 4194304 el)
    unsigned short* vt = (unsigned short*)(ws + 97 * MB);    // 8MB (qb + 8388608 el)
    float* sc = (float*)(ws + 105 * MB);                     // 4MB
    unsigned short* pbf = (unsigned short*)(ws + 109 * MB);  // 2MB
    unsigned short* xb2 = (unsigned short*)(ws + 111 * MB);  // 8MB (ends 119MB)

    // --- weight/activation prep ---
    k_cast<<<NN * F_IN / 1024, 256, 0, stream>>>(x, xb, NN * F_IN);
    hipMemsetAsync(wt_fc2p, 0, 128 * 512 * sizeof(unsigned short), stream);
    dim3 trb(32, 8);
    k_trz<0><<<dim3(16, 4), trb, 0, stream>>>(w_in, wt_in, F_IN, DD, 0, 0);
    k_trz<0><<<dim3(16, 16), trb, 0, stream>>>(w_mid, wt_mid, DD, DD, 0, 0);
    k_trz<0><<<dim3(16, 16), trb, 0, stream>>>(w_out, wt_out, DD, DD, 0, 0);
    k_trz<0><<<dim3(16, 16), trb, 0, stream>>>(fc1_w, wt_fc1, DD, DD, 0, 0);
    k_trz<0><<<dim3(1, 16), trb, 0, stream>>>(fc2_w, wt_fc2p, DD, 32, 0, 0);
    k_trz<1><<<dim3(32, 16, 3), trb, 0, stream>>>(qkv1_w, qkv1_8, DD, HH, 524288, 524288);
    k_trz<1><<<dim3(32, 32, 3), trb, 0, stream>>>(qkv2_w, qkv2_8, HH, HH, 1048576, 1048576);
    k_trz<1><<<dim3(16, 32, 3), trb, 0, stream>>>(qkv3_w, qkv3_8, HH, DD, 524288, 524288);

    // --- degree + CSR build ---
    k_zero_cnt<<<NN / 256, 256, 0, stream>>>(cnt);
    k_count<<<EE / 256, 256, 0, stream>>>(ei, cnt);
    k_scan<<<1, 1024, 0, stream>>>(cnt, off, pos, dinv);
    k_fill<<<EE / 256, 256, 0, stream>>>(ei, dinv, pos, csrc, cw);

    auto layer = [&](const unsigned short* hin, const unsigned short* wt,
                     const float* b, int Kin) {
        // GCN (bf16): xwb = hin @ w, aggregate -> g8 (fp8)
        gemm_mfma<0, 1, 1><<<dim3(4, 64), 256, 0, stream>>>(
            hin, wt, nullptr, xwb, Kin, Kin, Kin, 512, 512, 0, 0, 0, 0, 0);
        gcn_agg<<<NN, 256, 0, stream>>>(xwb, b, off, csrc, cw, dinv, g8);
        // qkv MLP in fp8: qkv1 wide (M=3072), qkv2 z=3, qkv3 z=3 (v transposed)
        gemm_f8<1, 10, 1><<<dim3(24, 64), 256, 0, stream>>>(
            g8, qkv1_8, qkv1_b, t1_8, 512, 512, 512, 3072, 3072, 0, 0, 0, 0);
        gemm_f8<1, 10, 1><<<dim3(8, 64, 3), 256, 0, stream>>>(
            t1_8, qkv2_8, qkv2_b, t2_8, 1024, 3072, 1024, 3072, 1024,
            1024, 1048576, 1024, 1024);
        gemm_f8<1, 3, 1><<<dim3(4, 64, 3), 256, 0, stream>>>(
            t2_8, qkv3_8, qkv3_b, qb, 1024, 3072, 1024, 512, 512,
            1024, 524288, 4194304, 512);
        // attention (bf16): scores (cross-doc via xorb), softmax, AV
        gemm_mfma<3, 0, 0><<<dim3(1, 1, NDOC), 256, 0, stream>>>(
            qb, kbb, nullptr, sc, 512, 512, 512, 128, 128,
            65536, 65536, 16384, 0, 1);
        softmax128<<<NDOC * 128, 64, 0, stream>>>(sc, pbf);
        gemm_mfma<0, 1, 0><<<dim3(4, 1, NDOC), 256, 0, stream>>>(
            pbf, vt, nullptr, h_b, 128, 128, 128, 512, 512,
            16384, 65536, 65536, 0, 1);
    };

    layer(xb, wt_in, b_in, F_IN);
    layer(h_b, wt_mid, b_mid, DD);
    layer(h_b, wt_mid, b_mid, DD);
    layer(h_b, wt_out, b_out, DD);

    // final FCs + pool + pairwise sigmoid
    gemm_mfma<2, 1, 1><<<dim3(4, 64), 256, 0, stream>>>(
        h_b, wt_fc1, fc1_b, xb2, 512, 512, 512, 512, 512, 0, 0, 0, 0, 0);
    gemm_mfma<2, 0, 1><<<dim3(1, 64), 256, 0, stream>>>(
        xb2, wt_fc2p, fc2_b, h32, 512, 512, 512, 32, 32, 0, 0, 0, 0, 0);
    pool_fc3<<<NDOC, 128, 0, stream>>>(h32, fc3_w, fc3_b, util);
    final_out<<<1, 64, 0, stream>>>(util, idx_a, idx_b, out);
}

// Round 8
// 753.687 us; speedup vs baseline: 1.7133x; 1.3430x over previous
//
#include <hip/hip_runtime.h>
#include <math.h>

#define NN 8192
#define NPD 128
#define F_IN 128
#define DD 512
#define HH 1024
#define EE 131072
#define NDOC 64
#define NPAIR 32

typedef __attribute__((ext_vector_type(8))) short bf16x8;
typedef __attribute__((ext_vector_type(4))) float f32x4;
typedef __attribute__((ext_vector_type(4))) int i32x4;
typedef __attribute__((ext_vector_type(8))) int i32x8;
typedef const __attribute__((address_space(1))) void* gas_ptr;
typedef __attribute__((address_space(3))) void* las_ptr;

__device__ __forceinline__ unsigned short f2b(float f) {
    union { float f; unsigned u; } v; v.f = f;
    unsigned r = v.u + 0x7fffu + ((v.u >> 16) & 1u);
    return (unsigned short)(r >> 16);
}
__device__ __forceinline__ float b2f_lo(unsigned u) {
    union { unsigned u; float f; } v; v.u = u << 16; return v.f;
}
__device__ __forceinline__ float b2f_hi(unsigned u) {
    union { unsigned u; float f; } v; v.u = u & 0xffff0000u; return v.f;
}
__device__ __forceinline__ unsigned char f2fp8(float f) {
    return (unsigned char)(__builtin_amdgcn_cvt_pk_fp8_f32(f, f, 0, false) & 0xff);
}

// ---------------------------------------------------------------------------
// Degree / CSR construction
// ---------------------------------------------------------------------------
__global__ void k_zero_cnt(int* __restrict__ cnt) {
    int i = blockIdx.x * 256 + threadIdx.x;
    if (i < NN) cnt[i] = 0;
}

__global__ void k_count(const int* __restrict__ ei, int* __restrict__ cnt) {
    int e = blockIdx.x * 256 + threadIdx.x;
    if (e < EE) atomicAdd(&cnt[ei[EE + e]], 1);
}

__global__ void k_scan(const int* __restrict__ cnt, int* __restrict__ off,
                       int* __restrict__ pos, float* __restrict__ dinv) {
    __shared__ int part[1024];
    int t = threadIdx.x;
    int loc[8];
    int s = 0;
    int base = t * 8;
#pragma unroll
    for (int j = 0; j < 8; ++j) {
        int c = cnt[base + j];
        dinv[base + j] = rsqrtf((float)c + 1.0f);
        loc[j] = s;
        s += c;
    }
    part[t] = s;
    __syncthreads();
    for (int st = 1; st < 1024; st <<= 1) {
        int v = (t >= st) ? part[t - st] : 0;
        __syncthreads();
        part[t] += v;
        __syncthreads();
    }
    int pre = (t > 0) ? part[t - 1] : 0;
#pragma unroll
    for (int j = 0; j < 8; ++j) {
        int val = pre + loc[j];
        off[base + j] = val;
        pos[base + j] = val;
    }
    if (t == 1023) off[NN] = part[1023];
}

__global__ void k_fill(const int* __restrict__ ei, const float* __restrict__ dinv,
                       int* __restrict__ pos, int* __restrict__ csr_src,
                       float* __restrict__ csr_w) {
    int e = blockIdx.x * 256 + threadIdx.x;
    if (e >= EE) return;
    int r = ei[e];
    int c = ei[EE + e];
    int p = atomicAdd(&pos[c], 1);
    csr_src[p] = r;
    csr_w[p] = dinv[r] * dinv[c];
}

// ---------------------------------------------------------------------------
__global__ void k_cast(const float* __restrict__ in, unsigned short* __restrict__ out,
                       int n) {
    int i = (blockIdx.x * 256 + threadIdx.x) * 4;
    if (i < n) {
        float4 v = *(const float4*)(in + i);
        out[i + 0] = f2b(v.x);
        out[i + 1] = f2b(v.y);
        out[i + 2] = f2b(v.z);
        out[i + 3] = f2b(v.w);
    }
}

// transpose W (K x M fp32) -> Wt (M x K), batched over z. F8: fp8 out else bf16.
template <int F8>
__global__ void k_trz(const float* __restrict__ in, void* __restrict__ outv,
                      int K, int M, long sin, long sout) {
    in += (size_t)blockIdx.z * sin;
    __shared__ float t[32][33];
    int bx = blockIdx.x * 32;
    int by = blockIdx.y * 32;
    int tx = threadIdx.x, ty = threadIdx.y;
    for (int i = ty; i < 32; i += 8)
        t[i][tx] = in[(size_t)(by + i) * M + bx + tx];
    __syncthreads();
    if (F8) {
        unsigned char* out = (unsigned char*)outv + (size_t)blockIdx.z * sout;
        for (int i = ty; i < 32; i += 8)
            out[(size_t)(bx + i) * K + by + tx] = f2fp8(t[tx][i]);
    } else {
        unsigned short* out = (unsigned short*)outv + (size_t)blockIdx.z * sout;
        for (int i = ty; i < 32; i += 8)
            out[(size_t)(bx + i) * K + by + tx] = f2b(t[tx][i]);
    }
}

// ---------------------------------------------------------------------------
// bf16 MFMA GEMM: C = act(A @ Bt^T + bias). 128x128 tile, BK=64,
// XOR bank-swizzled LDS. ACT: 0 none,1 relu,2 tanh,3 scale(1/sqrt512)
// OMODE: 0 fp32, 1 bf16, 3 bf16 but z==2 -> transposed-per-doc (vt)
// ---------------------------------------------------------------------------
template <int ACT, int OMODE, int SWZ>
__global__ __launch_bounds__(256) void gemm_mfma(
    const unsigned short* __restrict__ A, const unsigned short* __restrict__ Bt,
    const float* __restrict__ bias, void* __restrict__ Cout,
    int K, int lda, int ldbt, int ldc, int mreal,
    long saz, long sbz, long scz, int sbiasz, int xorb) {
    __shared__ unsigned short As[128 * 64];
    __shared__ unsigned short Bs[128 * 64];

    int bx = blockIdx.x, by = blockIdx.y, bz = blockIdx.z;
    if (SWZ) {
        const int nx = gridDim.x, ny = gridDim.y;
        const int band = ny >> 3;
        int b = (bz * ny + by) * nx + bx;
        const int k = b & 7;
        int s = b >> 3;
        bx = s % nx; s /= nx;
        const int yl = s % band; s /= band;
        bz = s;
        by = k * band + yl;
    }
    const int z = bz;
    A += (size_t)z * saz;
    Bt += (size_t)(z ^ xorb) * sbz;
    if (bias) bias += (size_t)z * sbiasz;

    const int tid = threadIdx.x;
    const int wave = tid >> 6, lane = tid & 63;
    const int m0 = by * 128;
    const int n0 = bx * 128;
    const int wm = (wave & 1) * 64, wn = (wave >> 1) * 64;
    const int lhi = lane >> 4;
    const int llo = lane & 15;
    f32x4 acc[4][4] = {};

    const int srow = lane >> 3;
    const int sseg = (lane & 7) ^ srow;
    const unsigned short* ag = A + (size_t)(m0 + wave * 32 + srow) * lda + sseg * 8;
    const unsigned short* bg = Bt + (size_t)(n0 + wave * 32 + srow) * ldbt + sseg * 8;
    unsigned short* al = As + wave * 2048;
    unsigned short* bl = Bs + wave * 2048;

    const int rxor = (llo & 7) * 8;

    for (int k0 = 0; k0 < K; k0 += 64) {
#pragma unroll
        for (int r = 0; r < 4; ++r) {
            __builtin_amdgcn_global_load_lds((gas_ptr)(ag + k0 + (size_t)r * 8 * lda),
                                             (las_ptr)(al + r * 512), 16, 0, 0);
            __builtin_amdgcn_global_load_lds((gas_ptr)(bg + k0 + (size_t)r * 8 * ldbt),
                                             (las_ptr)(bl + r * 512), 16, 0, 0);
        }
        __syncthreads();
#pragma unroll
        for (int s = 0; s < 2; ++s) {
            const int cofs = ((s * 4 + lhi) * 8) ^ rxor;
            bf16x8 af[4], bf[4];
#pragma unroll
            for (int i = 0; i < 4; ++i) {
                af[i] = *(const bf16x8*)(As + (wm + i * 16 + llo) * 64 + cofs);
                bf[i] = *(const bf16x8*)(Bs + (wn + i * 16 + llo) * 64 + cofs);
            }
#pragma unroll
            for (int i = 0; i < 4; ++i)
#pragma unroll
                for (int j = 0; j < 4; ++j)
                    acc[i][j] = __builtin_amdgcn_mfma_f32_16x16x32_bf16(af[i], bf[j],
                                                                        acc[i][j], 0, 0, 0);
        }
        __syncthreads();
    }

    float* Cf = (float*)Cout + (size_t)z * scz;
    unsigned short* Cb = (unsigned short*)Cout + (size_t)z * scz;
#pragma unroll
    for (int j = 0; j < 4; ++j) {
        const int col = n0 + wn + j * 16 + llo;
        if (col < mreal) {
            const float bv = bias ? bias[col] : 0.f;
#pragma unroll
            for (int i = 0; i < 4; ++i) {
                const int row = m0 + wm + i * 16 + lhi * 4;
                const int rloc = wm + i * 16 + lhi * 4;
#pragma unroll
                for (int r = 0; r < 4; ++r) {
                    float v = acc[i][j][r] + bv;
                    if (ACT == 1) v = fmaxf(v, 0.f);
                    if (ACT == 2) v = tanhf(v);
                    if (ACT == 3) v *= 0.044194173824159216f;
                    if (OMODE == 0) {
                        Cf[(size_t)(row + r) * ldc + col] = v;
                    } else if (OMODE == 1) {
                        Cb[(size_t)(row + r) * ldc + col] = f2b(v);
                    } else {
                        if (z < 2)
                            Cb[(size_t)(row + r) * ldc + col] = f2b(v);
                        else
                            Cb[(size_t)by * 65536 + (size_t)col * 128 + rloc + r] = f2b(v);
                    }
                }
            }
        }
    }
}

// ---------------------------------------------------------------------------
// MX-scaled fp8 MFMA GEMM (mfma_scale_f32_16x16x128_f8f6f4, scales = 1.0):
// C = act(A @ Bt^T + bias), A/Bt fp8 e4m3, K-contig. 128x128 tile, BK=128
// (one MFMA consumes the whole K-tile), XOR bank-swizzled staging identical
// to r7. Fragment: row = lane&15, k = (lane>>4)*32 + 0..31 -> two b128 reads
// whose 16-lane phases are conflict-free under the XOR swizzle.
// ACT: 1 relu. OMODE: 10 fp8 out, 3 bf16 out with z==2 -> vt transpose.
// ---------------------------------------------------------------------------
template <int ACT, int OMODE, int SWZ>
__global__ __launch_bounds__(256) void gemm_mx(
    const unsigned char* __restrict__ A, const unsigned char* __restrict__ Bt,
    const float* __restrict__ bias, void* __restrict__ Cout,
    int K, int lda, int ldbt, int ldc, int mreal,
    long saz, long sbz, long scz, int sbiasz) {
    __shared__ unsigned char As[128 * 128];
    __shared__ unsigned char Bs[128 * 128];

    int bx = blockIdx.x, by = blockIdx.y, bz = blockIdx.z;
    if (SWZ) {
        const int nx = gridDim.x, ny = gridDim.y;
        const int band = ny >> 3;
        int b = (bz * ny + by) * nx + bx;
        const int k = b & 7;
        int s = b >> 3;
        bx = s % nx; s /= nx;
        const int yl = s % band; s /= band;
        bz = s;
        by = k * band + yl;
    }
    const int z = bz;
    A += (size_t)z * saz;
    Bt += (size_t)z * sbz;
    if (bias) bias += (size_t)z * sbiasz;

    const int tid = threadIdx.x;
    const int wave = tid >> 6, lane = tid & 63;
    const int m0 = by * 128;
    const int n0 = bx * 128;
    const int wm = (wave & 1) * 64, wn = (wave >> 1) * 64;
    const int lhi = lane >> 4;
    const int llo = lane & 15;
    f32x4 acc[4][4] = {};

    // staging (identical to r7): LDS[row][slot] = global[row][slot ^ (row&7)]
    const int srow = lane >> 3;
    const int sseg = (lane & 7) ^ srow;
    const unsigned char* ag = A + (size_t)(m0 + wave * 32 + srow) * lda + sseg * 16;
    const unsigned char* bg = Bt + (size_t)(n0 + wave * 32 + srow) * ldbt + sseg * 16;
    unsigned char* al = As + wave * 4096;
    unsigned char* bl = Bs + wave * 4096;

    const int rx = llo & 7;           // read-side XOR key (row&7)
    const int s0 = (2 * lhi) ^ rx;    // seg of k-bytes [lhi*32, +16)
    const int s1 = (2 * lhi + 1) ^ rx;

    for (int k0 = 0; k0 < K; k0 += 128) {
#pragma unroll
        for (int r = 0; r < 4; ++r) {
            __builtin_amdgcn_global_load_lds((gas_ptr)(ag + k0 + (size_t)r * 8 * lda),
                                             (las_ptr)(al + r * 1024), 16, 0, 0);
            __builtin_amdgcn_global_load_lds((gas_ptr)(bg + k0 + (size_t)r * 8 * ldbt),
                                             (las_ptr)(bl + r * 1024), 16, 0, 0);
        }
        __syncthreads();
        i32x8 af[4], bf[4];
#pragma unroll
        for (int i = 0; i < 4; ++i) {
            const unsigned char* ra = As + (wm + i * 16 + llo) * 128;
            const unsigned char* rb = Bs + (wn + i * 16 + llo) * 128;
            i32x4 a_lo = *(const i32x4*)(ra + s0 * 16);
            i32x4 a_hi = *(const i32x4*)(ra + s1 * 16);
            i32x4 b_lo = *(const i32x4*)(rb + s0 * 16);
            i32x4 b_hi = *(const i32x4*)(rb + s1 * 16);
#pragma unroll
            for (int w = 0; w < 4; ++w) {
                af[i][w] = a_lo[w]; af[i][w + 4] = a_hi[w];
                bf[i][w] = b_lo[w]; bf[i][w + 4] = b_hi[w];
            }
        }
#pragma unroll
        for (int i = 0; i < 4; ++i)
#pragma unroll
            for (int j = 0; j < 4; ++j)
                acc[i][j] = __builtin_amdgcn_mfma_scale_f32_16x16x128_f8f6f4(
                    af[i], bf[j], acc[i][j], 0, 0, 0, 127, 0, 127);
        __syncthreads();
    }

    unsigned char* C8 = (unsigned char*)Cout + (size_t)z * scz;
    unsigned short* Cb = (unsigned short*)Cout + (size_t)z * scz;
#pragma unroll
    for (int j = 0; j < 4; ++j) {
        const int col = n0 + wn + j * 16 + llo;
        if (col < mreal) {
            const float bv = bias ? bias[col] : 0.f;
#pragma unroll
            for (int i = 0; i < 4; ++i) {
                const int row = m0 + wm + i * 16 + lhi * 4;
                const int rloc = wm + i * 16 + lhi * 4;
#pragma unroll
                for (int r = 0; r < 4; ++r) {
                    float v = acc[i][j][r] + bv;
                    if (ACT == 1) v = fmaxf(v, 0.f);
                    if (OMODE == 10) {
                        C8[(size_t)(row + r) * ldc + col] = f2fp8(v);
                    } else {  // OMODE 3: bf16; z==2 -> vt transpose
                        if (z < 2)
                            Cb[(size_t)(row + r) * ldc + col] = f2b(v);
                        else
                            Cb[(size_t)by * 65536 + (size_t)col * 128 + rloc + r] = f2b(v);
                    }
                }
            }
        }
    }
}

// ---------------------------------------------------------------------------
// GCN aggregation (bf16 in, fp8 out): out = tanh(sum w*xw[src] + dinv^2*xw + b)
// ---------------------------------------------------------------------------
__global__ __launch_bounds__(256) void gcn_agg(const unsigned short* __restrict__ xwb,
                                               const float* __restrict__ bias,
                                               const int* __restrict__ off,
                                               const int* __restrict__ src,
                                               const float* __restrict__ wgt,
                                               const float* __restrict__ dinv,
                                               unsigned char* __restrict__ out) {
    const int node = blockIdx.x;
    const int t = threadIdx.x;
    const int d0 = 2 * t;
    const int beg = off[node], end = off[node + 1];
    float a0 = 0.f, a1 = 0.f;
    int e = beg;
    for (; e + 1 < end; e += 2) {
        const int s0 = src[e], s1 = src[e + 1];
        const float w0 = wgt[e], w1 = wgt[e + 1];
        const unsigned u0 = *(const unsigned*)(xwb + (size_t)s0 * DD + d0);
        const unsigned u1 = *(const unsigned*)(xwb + (size_t)s1 * DD + d0);
        a0 += w0 * b2f_lo(u0) + w1 * b2f_lo(u1);
        a1 += w0 * b2f_hi(u0) + w1 * b2f_hi(u1);
    }
    if (e < end) {
        const int s0 = src[e];
        const float w0 = wgt[e];
        const unsigned u0 = *(const unsigned*)(xwb + (size_t)s0 * DD + d0);
        a0 += w0 * b2f_lo(u0);
        a1 += w0 * b2f_hi(u0);
    }
    const float ns = dinv[node] * dinv[node];
    const unsigned un = *(const unsigned*)(xwb + (size_t)node * DD + d0);
    const float r0 = tanhf(a0 + ns * b2f_lo(un) + bias[d0]);
    const float r1 = tanhf(a1 + ns * b2f_hi(un) + bias[d0 + 1]);
    unsigned p = (unsigned)__builtin_amdgcn_cvt_pk_fp8_f32(r0, r1, 0, false);
    *(unsigned short*)(out + (size_t)node * DD + d0) = (unsigned short)(p & 0xffff);
}

// ---------------------------------------------------------------------------
__global__ __launch_bounds__(64) void softmax128(const float* __restrict__ sc,
                                                 unsigned short* __restrict__ p) {
    const int row = blockIdx.x;
    const float* ip = sc + (size_t)row * 128;
    unsigned short* op = p + (size_t)row * 128;
    const int l = threadIdx.x;
    float a = ip[l], b = ip[l + 64];
    float m = fmaxf(a, b);
#pragma unroll
    for (int s = 32; s; s >>= 1) m = fmaxf(m, __shfl_xor(m, s));
    float e0 = expf(a - m), e1 = expf(b - m);
    float sum = e0 + e1;
#pragma unroll
    for (int s = 32; s; s >>= 1) sum += __shfl_xor(sum, s);
    float inv = 1.f / sum;
    op[l] = f2b(e0 * inv);
    op[l + 64] = f2b(e1 * inv);
}

// ---------------------------------------------------------------------------
__global__ __launch_bounds__(128) void pool_fc3(const float* __restrict__ h32,
                                                const float* __restrict__ w3,
                                                const float* __restrict__ b3,
                                                float* __restrict__ util) {
    const int doc = blockIdx.x;
    const int t = threadIdx.x;
    const float* hp = h32 + (size_t)(doc * 128 + t) * 32;
    float s = 0.f;
#pragma unroll
    for (int j = 0; j < 32; ++j) s += hp[j] * w3[j];
    s += b3[0];
    __shared__ float red[128];
    red[t] = s;
    __syncthreads();
    for (int k = 64; k > 0; k >>= 1) {
        if (t < k) red[t] += red[t + k];
        __syncthreads();
    }
    if (t == 0) util[doc] = red[0] * (1.0f / 128.0f);
}

__global__ void final_out(const float* __restrict__ util, const int* __restrict__ ia,
                          const int* __restrict__ ib, float* __restrict__ out) {
    int i = threadIdx.x;
    if (i < NPAIR) {
        float z = util[ib[i]] - util[ia[i]];
        out[i] = 1.f / (1.f + expf(-z));
    }
}

// ---------------------------------------------------------------------------
extern "C" void kernel_launch(void* const* d_in, const int* in_sizes, int n_in,
                              void* d_out, int out_size, void* d_ws, size_t ws_size,
                              hipStream_t stream) {
    const float* x = (const float*)d_in[0];
    const float* w_in = (const float*)d_in[1];
    const float* b_in = (const float*)d_in[2];
    const float* w_mid = (const float*)d_in[3];
    const float* b_mid = (const float*)d_in[4];
    const float* w_out = (const float*)d_in[5];
    const float* b_out = (const float*)d_in[6];
    const float* fc1_w = (const float*)d_in[7];
    const float* fc1_b = (const float*)d_in[8];
    const float* fc2_w = (const float*)d_in[9];
    const float* fc2_b = (const float*)d_in[10];
    const float* fc3_w = (const float*)d_in[11];
    const float* fc3_b = (const float*)d_in[12];
    const float* qkv1_w = (const float*)d_in[13];
    const float* qkv1_b = (const float*)d_in[14];
    const float* qkv2_w = (const float*)d_in[15];
    const float* qkv2_b = (const float*)d_in[16];
    const float* qkv3_w = (const float*)d_in[17];
    const float* qkv3_b = (const float*)d_in[18];
    const int* ei = (const int*)d_in[19];
    const int* idx_a = (const int*)d_in[22];
    const int* idx_b = (const int*)d_in[23];
    float* out = (float*)d_out;

    char* ws = (char*)d_ws;
    const size_t MB = 1024 * 1024;
    const size_t KB = 1024;
    float* dinv = (float*)(ws + 0);
    int* cnt = (int*)(ws + 64 * KB);
    int* off = (int*)(ws + 128 * KB);
    int* pos = (int*)(ws + 192 * KB);
    int* csrc = (int*)(ws + 256 * KB);
    float* cw = (float*)(ws + 768 * KB);
    float* util = (float*)(ws + 1280 * KB);
    unsigned short* xb = (unsigned short*)(ws + 2 * MB);   // 2MB (8192x128 bf16)
    float* h32 = (float*)(ws + 2 * MB);                    // alias, live after layers
    unsigned short* wt_in = (unsigned short*)(ws + 4 * MB);                // 128KB
    unsigned short* wt_mid = (unsigned short*)(ws + 4 * MB + 128 * KB);    // 512KB
    unsigned short* wt_out = (unsigned short*)(ws + 4 * MB + 640 * KB);    // 512KB
    unsigned short* wt_fc1 = (unsigned short*)(ws + 4 * MB + 1152 * KB);   // 512KB
    unsigned short* wt_fc2p = (unsigned short*)(ws + 4 * MB + 1664 * KB);  // 128KB
    unsigned char* qkv1_8 = (unsigned char*)(ws + 6 * MB);   // 1.5MB (3072x512)
    unsigned char* qkv2_8 = (unsigned char*)(ws + 8 * MB);   // 3MB (3x1024x1024)
    unsigned char* qkv3_8 = (unsigned char*)(ws + 11 * MB);  // 1.5MB (3x512x1024)
    unsigned short* h_b = (unsigned short*)(ws + 13 * MB);   // 8MB bf16
    unsigned char* g8 = (unsigned char*)(ws + 21 * MB);      // 4MB fp8 (8192x512)
    unsigned char* t1_8 = (unsigned char*)(ws + 25 * MB);    // 24MB (8192x3072)
    unsigned char* t2_8 = (unsigned char*)(ws + 49 * MB);    // 24MB
    unsigned short* xwb = (unsigned short*)(ws + 73 * MB);   // 8MB bf16
    unsigned short* qb = (unsigned short*)(ws + 81 * MB);    // 8MB
    unsigned short* kbb = (unsigned short*)(ws + 89 * MB);   // 8MB (qb + 4194304 el)
    unsigned short* vt = (unsigned short*)(ws + 97 * MB);    // 8MB (qb + 8388608 el)
    float* sc = (float*)(ws + 105 * MB);                     // 4MB
    unsigned short* pbf = (unsigned short*)(ws + 109 * MB);  // 2MB
    unsigned short* xb2 = (unsigned short*)(ws + 111 * MB);  // 8MB (ends 119MB)

    // --- weight/activation prep ---
    k_cast<<<NN * F_IN / 1024, 256, 0, stream>>>(x, xb, NN * F_IN);
    hipMemsetAsync(wt_fc2p, 0, 128 * 512 * sizeof(unsigned short), stream);
    dim3 trb(32, 8);
    k_trz<0><<<dim3(16, 4), trb, 0, stream>>>(w_in, wt_in, F_IN, DD, 0, 0);
    k_trz<0><<<dim3(16, 16), trb, 0, stream>>>(w_mid, wt_mid, DD, DD, 0, 0);
    k_trz<0><<<dim3(16, 16), trb, 0, stream>>>(w_out, wt_out, DD, DD, 0, 0);
    k_trz<0><<<dim3(16, 16), trb, 0, stream>>>(fc1_w, wt_fc1, DD, DD, 0, 0);
    k_trz<0><<<dim3(1, 16), trb, 0, stream>>>(fc2_w, wt_fc2p, DD, 32, 0, 0);
    k_trz<1><<<dim3(32, 16, 3), trb, 0, stream>>>(qkv1_w, qkv1_8, DD, HH, 524288, 524288);
    k_trz<1><<<dim3(32, 32, 3), trb, 0, stream>>>(qkv2_w, qkv2_8, HH, HH, 1048576, 1048576);
    k_trz<1><<<dim3(16, 32, 3), trb, 0, stream>>>(qkv3_w, qkv3_8, HH, DD, 524288, 524288);

    // --- degree + CSR build ---
    k_zero_cnt<<<NN / 256, 256, 0, stream>>>(cnt);
    k_count<<<EE / 256, 256, 0, stream>>>(ei, cnt);
    k_scan<<<1, 1024, 0, stream>>>(cnt, off, pos, dinv);
    k_fill<<<EE / 256, 256, 0, stream>>>(ei, dinv, pos, csrc, cw);

    auto layer = [&](const unsigned short* hin, const unsigned short* wt,
                     const float* b, int Kin) {
        // GCN (bf16): xwb = hin @ w, aggregate -> g8 (fp8)
        gemm_mfma<0, 1, 1><<<dim3(4, 64), 256, 0, stream>>>(
            hin, wt, nullptr, xwb, Kin, Kin, Kin, 512, 512, 0, 0, 0, 0, 0);
        gcn_agg<<<NN, 256, 0, stream>>>(xwb, b, off, csrc, cw, dinv, g8);
        // qkv MLP in MX-fp8: qkv1 wide (M=3072), qkv2 z=3, qkv3 z=3 (v transposed)
        gemm_mx<1, 10, 1><<<dim3(24, 64), 256, 0, stream>>>(
            g8, qkv1_8, qkv1_b, t1_8, 512, 512, 512, 3072, 3072, 0, 0, 0, 0);
        gemm_mx<1, 10, 1><<<dim3(8, 64, 3), 256, 0, stream>>>(
            t1_8, qkv2_8, qkv2_b, t2_8, 1024, 3072, 1024, 3072, 1024,
            1024, 1048576, 1024, 1024);
        gemm_mx<1, 3, 1><<<dim3(4, 64, 3), 256, 0, stream>>>(
            t2_8, qkv3_8, qkv3_b, qb, 1024, 3072, 1024, 512, 512,
            1024, 524288, 4194304, 512);
        // attention (bf16): scores (cross-doc via xorb), softmax, AV
        gemm_mfma<3, 0, 0><<<dim3(1, 1, NDOC), 256, 0, stream>>>(
            qb, kbb, nullptr, sc, 512, 512, 512, 128, 128,
            65536, 65536, 16384, 0, 1);
        softmax128<<<NDOC * 128, 64, 0, stream>>>(sc, pbf);
        gemm_mfma<0, 1, 0><<<dim3(4, 1, NDOC), 256, 0, stream>>>(
            pbf, vt, nullptr, h_b, 128, 128, 128, 512, 512,
            16384, 65536, 65536, 0, 1);
    };

    layer(xb, wt_in, b_in, F_IN);
    layer(h_b, wt_mid, b_mid, DD);
    layer(h_b, wt_mid, b_mid, DD);
    layer(h_b, wt_out, b_out, DD);

    // final FCs + pool + pairwise sigmoid
    gemm_mfma<2, 1, 1><<<dim3(4, 64), 256, 0, stream>>>(
        h_b, wt_fc1, fc1_b, xb2, 512, 512, 512, 512, 512, 0, 0, 0, 0, 0);
    gemm_mfma<2, 0, 1><<<dim3(1, 64), 256, 0, stream>>>(
        xb2, wt_fc2p, fc2_b, h32, 512, 512, 512, 32, 32, 0, 0, 0, 0, 0);
    pool_fc3<<<NDOC, 128, 0, stream>>>(h32, fc3_w, fc3_b, util);
    final_out<<<1, 64, 0, stream>>>(util, idx_a, idx_b, out);
}

// Round 9
// 708.912 us; speedup vs baseline: 1.8215x; 1.0632x over previous
//
#include <hip/hip_runtime.h>
#include <math.h>

#define NN 8192
#define NPD 128
#define F_IN 128
#define DD 512
#define HH 1024
#define EE 131072
#define NDOC 64
#define NPAIR 32

typedef __attribute__((ext_vector_type(8))) short bf16x8;
typedef __attribute__((ext_vector_type(4))) float f32x4;
typedef __attribute__((ext_vector_type(4))) int i32x4;
typedef __attribute__((ext_vector_type(8))) int i32x8;
typedef const __attribute__((address_space(1))) void* gas_ptr;
typedef __attribute__((address_space(3))) void* las_ptr;

__device__ __forceinline__ unsigned short f2b(float f) {
    union { float f; unsigned u; } v; v.f = f;
    unsigned r = v.u + 0x7fffu + ((v.u >> 16) & 1u);
    return (unsigned short)(r >> 16);
}
__device__ __forceinline__ unsigned char f2fp8(float f) {
    return (unsigned char)(__builtin_amdgcn_cvt_pk_fp8_f32(f, f, 0, false) & 0xff);
}

// ---------------------------------------------------------------------------
// Degree / CSR construction
// ---------------------------------------------------------------------------
__global__ void k_zero_cnt(int* __restrict__ cnt) {
    int i = blockIdx.x * 256 + threadIdx.x;
    if (i < NN) cnt[i] = 0;
}

__global__ void k_count(const int* __restrict__ ei, int* __restrict__ cnt) {
    int e = blockIdx.x * 256 + threadIdx.x;
    if (e < EE) atomicAdd(&cnt[ei[EE + e]], 1);
}

__global__ void k_scan(const int* __restrict__ cnt, int* __restrict__ off,
                       int* __restrict__ pos, float* __restrict__ dinv) {
    __shared__ int part[1024];
    int t = threadIdx.x;
    int loc[8];
    int s = 0;
    int base = t * 8;
#pragma unroll
    for (int j = 0; j < 8; ++j) {
        int c = cnt[base + j];
        dinv[base + j] = rsqrtf((float)c + 1.0f);
        loc[j] = s;
        s += c;
    }
    part[t] = s;
    __syncthreads();
    for (int st = 1; st < 1024; st <<= 1) {
        int v = (t >= st) ? part[t - st] : 0;
        __syncthreads();
        part[t] += v;
        __syncthreads();
    }
    int pre = (t > 0) ? part[t - 1] : 0;
#pragma unroll
    for (int j = 0; j < 8; ++j) {
        int val = pre + loc[j];
        off[base + j] = val;
        pos[base + j] = val;
    }
    if (t == 1023) off[NN] = part[1023];
}

__global__ void k_fill(const int* __restrict__ ei, const float* __restrict__ dinv,
                       int* __restrict__ pos, int* __restrict__ csr_src,
                       float* __restrict__ csr_w) {
    int e = blockIdx.x * 256 + threadIdx.x;
    if (e >= EE) return;
    int r = ei[e];
    int c = ei[EE + e];
    int p = atomicAdd(&pos[c], 1);
    csr_src[p] = r;
    csr_w[p] = dinv[r] * dinv[c];
}

// ---------------------------------------------------------------------------
// fp32 -> fp8 cast (x input)
__global__ void k_cast8(const float* __restrict__ in, unsigned char* __restrict__ out,
                        int n) {
    int i = (blockIdx.x * 256 + threadIdx.x) * 4;
    if (i < n) {
        float4 v = *(const float4*)(in + i);
        unsigned lo = (unsigned)__builtin_amdgcn_cvt_pk_fp8_f32(v.x, v.y, 0, false) & 0xffffu;
        unsigned hi = (unsigned)__builtin_amdgcn_cvt_pk_fp8_f32(v.z, v.w, 0, false) & 0xffffu;
        *(unsigned*)(out + i) = lo | (hi << 16);
    }
}

// transpose W (K x M fp32) -> Wt (M x K), batched over z. F8: fp8 out else bf16.
template <int F8>
__global__ void k_trz(const float* __restrict__ in, void* __restrict__ outv,
                      int K, int M, long sin, long sout) {
    in += (size_t)blockIdx.z * sin;
    __shared__ float t[32][33];
    int bx = blockIdx.x * 32;
    int by = blockIdx.y * 32;
    int tx = threadIdx.x, ty = threadIdx.y;
    for (int i = ty; i < 32; i += 8)
        t[i][tx] = in[(size_t)(by + i) * M + bx + tx];
    __syncthreads();
    if (F8) {
        unsigned char* out = (unsigned char*)outv + (size_t)blockIdx.z * sout;
        for (int i = ty; i < 32; i += 8)
            out[(size_t)(bx + i) * K + by + tx] = f2fp8(t[tx][i]);
    } else {
        unsigned short* out = (unsigned short*)outv + (size_t)blockIdx.z * sout;
        for (int i = ty; i < 32; i += 8)
            out[(size_t)(bx + i) * K + by + tx] = f2b(t[tx][i]);
    }
}

// ---------------------------------------------------------------------------
// bf16 MFMA GEMM (kept for fc1/fc2): C = act(A @ Bt^T + bias). 128x128 tile,
// BK=64, XOR bank-swizzled LDS. ACT: 0 none,1 relu,2 tanh. OMODE: 0 fp32, 1 bf16
// ---------------------------------------------------------------------------
template <int ACT, int OMODE, int SWZ>
__global__ __launch_bounds__(256) void gemm_mfma(
    const unsigned short* __restrict__ A, const unsigned short* __restrict__ Bt,
    const float* __restrict__ bias, void* __restrict__ Cout,
    int K, int lda, int ldbt, int ldc, int mreal,
    long saz, long sbz, long scz, int sbiasz, int xorb) {
    __shared__ unsigned short As[128 * 64];
    __shared__ unsigned short Bs[128 * 64];

    int bx = blockIdx.x, by = blockIdx.y, bz = blockIdx.z;
    if (SWZ) {
        const int nx = gridDim.x, ny = gridDim.y;
        const int band = ny >> 3;
        int b = (bz * ny + by) * nx + bx;
        const int k = b & 7;
        int s = b >> 3;
        bx = s % nx; s /= nx;
        const int yl = s % band; s /= band;
        bz = s;
        by = k * band + yl;
    }
    const int z = bz;
    A += (size_t)z * saz;
    Bt += (size_t)(z ^ xorb) * sbz;
    if (bias) bias += (size_t)z * sbiasz;

    const int tid = threadIdx.x;
    const int wave = tid >> 6, lane = tid & 63;
    const int m0 = by * 128;
    const int n0 = bx * 128;
    const int wm = (wave & 1) * 64, wn = (wave >> 1) * 64;
    const int lhi = lane >> 4;
    const int llo = lane & 15;
    f32x4 acc[4][4] = {};

    const int srow = lane >> 3;
    const int sseg = (lane & 7) ^ srow;
    const unsigned short* ag = A + (size_t)(m0 + wave * 32 + srow) * lda + sseg * 8;
    const unsigned short* bg = Bt + (size_t)(n0 + wave * 32 + srow) * ldbt + sseg * 8;
    unsigned short* al = As + wave * 2048;
    unsigned short* bl = Bs + wave * 2048;

    const int rxor = (llo & 7) * 8;

    for (int k0 = 0; k0 < K; k0 += 64) {
#pragma unroll
        for (int r = 0; r < 4; ++r) {
            __builtin_amdgcn_global_load_lds((gas_ptr)(ag + k0 + (size_t)r * 8 * lda),
                                             (las_ptr)(al + r * 512), 16, 0, 0);
            __builtin_amdgcn_global_load_lds((gas_ptr)(bg + k0 + (size_t)r * 8 * ldbt),
                                             (las_ptr)(bl + r * 512), 16, 0, 0);
        }
        __syncthreads();
#pragma unroll
        for (int s = 0; s < 2; ++s) {
            const int cofs = ((s * 4 + lhi) * 8) ^ rxor;
            bf16x8 af[4], bf[4];
#pragma unroll
            for (int i = 0; i < 4; ++i) {
                af[i] = *(const bf16x8*)(As + (wm + i * 16 + llo) * 64 + cofs);
                bf[i] = *(const bf16x8*)(Bs + (wn + i * 16 + llo) * 64 + cofs);
            }
#pragma unroll
            for (int i = 0; i < 4; ++i)
#pragma unroll
                for (int j = 0; j < 4; ++j)
                    acc[i][j] = __builtin_amdgcn_mfma_f32_16x16x32_bf16(af[i], bf[j],
                                                                        acc[i][j], 0, 0, 0);
        }
        __syncthreads();
    }

    float* Cf = (float*)Cout + (size_t)z * scz;
    unsigned short* Cb = (unsigned short*)Cout + (size_t)z * scz;
#pragma unroll
    for (int j = 0; j < 4; ++j) {
        const int col = n0 + wn + j * 16 + llo;
        if (col < mreal) {
            const float bv = bias ? bias[col] : 0.f;
#pragma unroll
            for (int i = 0; i < 4; ++i) {
                const int row = m0 + wm + i * 16 + lhi * 4;
#pragma unroll
                for (int r = 0; r < 4; ++r) {
                    float v = acc[i][j][r] + bv;
                    if (ACT == 1) v = fmaxf(v, 0.f);
                    if (ACT == 2) v = tanhf(v);
                    if (OMODE == 0)
                        Cf[(size_t)(row + r) * ldc + col] = v;
                    else
                        Cb[(size_t)(row + r) * ldc + col] = f2b(v);
                }
            }
        }
    }
}

// ---------------------------------------------------------------------------
// MX-scaled fp8 MFMA GEMM (scales=1.0): C = act(A @ Bt^T + bias).
// 128x128 tile, BK=128, XOR bank-swizzled staging (verified r8).
// ACT: 0 none, 1 relu, 3 scale(1/sqrt512)
// OMODE: 0 fp32 out; 10 fp8 out; 3 fp8 out with z==2 -> transposed-per-doc;
//        12 bf16 out + fp8 shadow (Cout2)
// xorb: B z-index = z ^ xorb (cross-doc attention)
// ---------------------------------------------------------------------------
template <int ACT, int OMODE, int SWZ>
__global__ __launch_bounds__(256) void gemm_mx(
    const unsigned char* __restrict__ A, const unsigned char* __restrict__ Bt,
    const float* __restrict__ bias, void* __restrict__ Cout,
    int K, int lda, int ldbt, int ldc, int mreal,
    long saz, long sbz, long scz, int sbiasz, int xorb, void* __restrict__ Cout2) {
    __shared__ unsigned char As[128 * 128];
    __shared__ unsigned char Bs[128 * 128];

    int bx = blockIdx.x, by = blockIdx.y, bz = blockIdx.z;
    if (SWZ) {
        const int nx = gridDim.x, ny = gridDim.y;
        const int band = ny >> 3;
        int b = (bz * ny + by) * nx + bx;
        const int k = b & 7;
        int s = b >> 3;
        bx = s % nx; s /= nx;
        const int yl = s % band; s /= band;
        bz = s;
        by = k * band + yl;
    }
    const int z = bz;
    A += (size_t)z * saz;
    Bt += (size_t)(z ^ xorb) * sbz;
    if (bias) bias += (size_t)z * sbiasz;

    const int tid = threadIdx.x;
    const int wave = tid >> 6, lane = tid & 63;
    const int m0 = by * 128;
    const int n0 = bx * 128;
    const int wm = (wave & 1) * 64, wn = (wave >> 1) * 64;
    const int lhi = lane >> 4;
    const int llo = lane & 15;
    f32x4 acc[4][4] = {};

    const int srow = lane >> 3;
    const int sseg = (lane & 7) ^ srow;
    const unsigned char* ag = A + (size_t)(m0 + wave * 32 + srow) * lda + sseg * 16;
    const unsigned char* bg = Bt + (size_t)(n0 + wave * 32 + srow) * ldbt + sseg * 16;
    unsigned char* al = As + wave * 4096;
    unsigned char* bl = Bs + wave * 4096;

    const int rx = llo & 7;
    const int s0 = (2 * lhi) ^ rx;
    const int s1 = (2 * lhi + 1) ^ rx;

    for (int k0 = 0; k0 < K; k0 += 128) {
#pragma unroll
        for (int r = 0; r < 4; ++r) {
            __builtin_amdgcn_global_load_lds((gas_ptr)(ag + k0 + (size_t)r * 8 * lda),
                                             (las_ptr)(al + r * 1024), 16, 0, 0);
            __builtin_amdgcn_global_load_lds((gas_ptr)(bg + k0 + (size_t)r * 8 * ldbt),
                                             (las_ptr)(bl + r * 1024), 16, 0, 0);
        }
        __syncthreads();
        i32x8 af[4], bf[4];
#pragma unroll
        for (int i = 0; i < 4; ++i) {
            const unsigned char* ra = As + (wm + i * 16 + llo) * 128;
            const unsigned char* rb = Bs + (wn + i * 16 + llo) * 128;
            i32x4 a_lo = *(const i32x4*)(ra + s0 * 16);
            i32x4 a_hi = *(const i32x4*)(ra + s1 * 16);
            i32x4 b_lo = *(const i32x4*)(rb + s0 * 16);
            i32x4 b_hi = *(const i32x4*)(rb + s1 * 16);
#pragma unroll
            for (int w = 0; w < 4; ++w) {
                af[i][w] = a_lo[w]; af[i][w + 4] = a_hi[w];
                bf[i][w] = b_lo[w]; bf[i][w + 4] = b_hi[w];
            }
        }
#pragma unroll
        for (int i = 0; i < 4; ++i)
#pragma unroll
            for (int j = 0; j < 4; ++j)
                acc[i][j] = __builtin_amdgcn_mfma_scale_f32_16x16x128_f8f6f4(
                    af[i], bf[j], acc[i][j], 0, 0, 0, 127, 0, 127);
        __syncthreads();
    }

    float* Cf = (float*)Cout + (size_t)z * scz;
    unsigned char* C8 = (unsigned char*)Cout + (size_t)z * scz;
    unsigned short* Cb = (unsigned short*)Cout + (size_t)z * scz;
    unsigned char* C2 = (OMODE == 12) ? (unsigned char*)Cout2 + (size_t)z * scz : nullptr;
#pragma unroll
    for (int j = 0; j < 4; ++j) {
        const int col = n0 + wn + j * 16 + llo;
        if (col < mreal) {
            const float bv = bias ? bias[col] : 0.f;
#pragma unroll
            for (int i = 0; i < 4; ++i) {
                const int row = m0 + wm + i * 16 + lhi * 4;
                const int rloc = wm + i * 16 + lhi * 4;
#pragma unroll
                for (int r = 0; r < 4; ++r) {
                    float v = acc[i][j][r] + bv;
                    if (ACT == 1) v = fmaxf(v, 0.f);
                    if (ACT == 3) v *= 0.044194173824159216f;
                    if (OMODE == 0) {
                        Cf[(size_t)(row + r) * ldc + col] = v;
                    } else if (OMODE == 10) {
                        C8[(size_t)(row + r) * ldc + col] = f2fp8(v);
                    } else if (OMODE == 3) {
                        if (z < 2)
                            C8[(size_t)(row + r) * ldc + col] = f2fp8(v);
                        else
                            C8[(size_t)by * 65536 + (size_t)col * 128 + rloc + r] = f2fp8(v);
                    } else {  // 12: bf16 + fp8 shadow
                        Cb[(size_t)(row + r) * ldc + col] = f2b(v);
                        C2[(size_t)(row + r) * ldc + col] = f2fp8(v);
                    }
                }
            }
        }
    }
}

// ---------------------------------------------------------------------------
// GCN aggregation (fp8 in, fp8 out): out = tanh(sum w*xw[src] + dinv^2*xw + b)
// thread t handles dims 2t, 2t+1; fp8 pair unpacked via v_cvt_pk_f32_fp8
// ---------------------------------------------------------------------------
__global__ __launch_bounds__(256) void gcn_agg(const unsigned char* __restrict__ xw8,
                                               const float* __restrict__ bias,
                                               const int* __restrict__ off,
                                               const int* __restrict__ src,
                                               const float* __restrict__ wgt,
                                               const float* __restrict__ dinv,
                                               unsigned char* __restrict__ out) {
    const int node = blockIdx.x;
    const int t = threadIdx.x;
    const int d0 = 2 * t;
    const int beg = off[node], end = off[node + 1];
    float a0 = 0.f, a1 = 0.f;
    int e = beg;
    for (; e + 1 < end; e += 2) {
        const int s0 = src[e], s1 = src[e + 1];
        const float w0 = wgt[e], w1 = wgt[e + 1];
        const unsigned u0 = *(const unsigned short*)(xw8 + (size_t)s0 * DD + d0);
        const unsigned u1 = *(const unsigned short*)(xw8 + (size_t)s1 * DD + d0);
        auto f0 = __builtin_amdgcn_cvt_pk_f32_fp8(u0, false);
        auto f1 = __builtin_amdgcn_cvt_pk_f32_fp8(u1, false);
        a0 += w0 * f0[0] + w1 * f1[0];
        a1 += w0 * f0[1] + w1 * f1[1];
    }
    if (e < end) {
        const int s0 = src[e];
        const float w0 = wgt[e];
        const unsigned u0 = *(const unsigned short*)(xw8 + (size_t)s0 * DD + d0);
        auto f0 = __builtin_amdgcn_cvt_pk_f32_fp8(u0, false);
        a0 += w0 * f0[0];
        a1 += w0 * f0[1];
    }
    const float ns = dinv[node] * dinv[node];
    const unsigned un = *(const unsigned short*)(xw8 + (size_t)node * DD + d0);
    auto fn = __builtin_amdgcn_cvt_pk_f32_fp8(un, false);
    const float r0 = tanhf(a0 + ns * fn[0] + bias[d0]);
    const float r1 = tanhf(a1 + ns * fn[1] + bias[d0 + 1]);
    unsigned p = (unsigned)__builtin_amdgcn_cvt_pk_fp8_f32(r0, r1, 0, false);
    *(unsigned short*)(out + (size_t)node * DD + d0) = (unsigned short)(p & 0xffff);
}

// ---------------------------------------------------------------------------
// softmax over rows of 128 (fp32 in, fp8 out); one wave per row
// ---------------------------------------------------------------------------
__global__ __launch_bounds__(64) void softmax128(const float* __restrict__ sc,
                                                 unsigned char* __restrict__ p) {
    const int row = blockIdx.x;
    const float* ip = sc + (size_t)row * 128;
    unsigned char* op = p + (size_t)row * 128;
    const int l = threadIdx.x;
    float a = ip[l], b = ip[l + 64];
    float m = fmaxf(a, b);
#pragma unroll
    for (int s = 32; s; s >>= 1) m = fmaxf(m, __shfl_xor(m, s));
    float e0 = expf(a - m), e1 = expf(b - m);
    float sum = e0 + e1;
#pragma unroll
    for (int s = 32; s; s >>= 1) sum += __shfl_xor(sum, s);
    float inv = 1.f / sum;
    op[l] = f2fp8(e0 * inv);
    op[l + 64] = f2fp8(e1 * inv);
}

// ---------------------------------------------------------------------------
__global__ __launch_bounds__(128) void pool_fc3(const float* __restrict__ h32,
                                                const float* __restrict__ w3,
                                                const float* __restrict__ b3,
                                                float* __restrict__ util) {
    const int doc = blockIdx.x;
    const int t = threadIdx.x;
    const float* hp = h32 + (size_t)(doc * 128 + t) * 32;
    float s = 0.f;
#pragma unroll
    for (int j = 0; j < 32; ++j) s += hp[j] * w3[j];
    s += b3[0];
    __shared__ float red[128];
    red[t] = s;
    __syncthreads();
    for (int k = 64; k > 0; k >>= 1) {
        if (t < k) red[t] += red[t + k];
        __syncthreads();
    }
    if (t == 0) util[doc] = red[0] * (1.0f / 128.0f);
}

__global__ void final_out(const float* __restrict__ util, const int* __restrict__ ia,
                          const int* __restrict__ ib, float* __restrict__ out) {
    int i = threadIdx.x;
    if (i < NPAIR) {
        float z = util[ib[i]] - util[ia[i]];
        out[i] = 1.f / (1.f + expf(-z));
    }
}

// ---------------------------------------------------------------------------
extern "C" void kernel_launch(void* const* d_in, const int* in_sizes, int n_in,
                              void* d_out, int out_size, void* d_ws, size_t ws_size,
                              hipStream_t stream) {
    const float* x = (const float*)d_in[0];
    const float* w_in = (const float*)d_in[1];
    const float* b_in = (const float*)d_in[2];
    const float* w_mid = (const float*)d_in[3];
    const float* b_mid = (const float*)d_in[4];
    const float* w_out = (const float*)d_in[5];
    const float* b_out = (const float*)d_in[6];
    const float* fc1_w = (const float*)d_in[7];
    const float* fc1_b = (const float*)d_in[8];
    const float* fc2_w = (const float*)d_in[9];
    const float* fc2_b = (const float*)d_in[10];
    const float* fc3_w = (const float*)d_in[11];
    const float* fc3_b = (const float*)d_in[12];
    const float* qkv1_w = (const float*)d_in[13];
    const float* qkv1_b = (const float*)d_in[14];
    const float* qkv2_w = (const float*)d_in[15];
    const float* qkv2_b = (const float*)d_in[16];
    const float* qkv3_w = (const float*)d_in[17];
    const float* qkv3_b = (const float*)d_in[18];
    const int* ei = (const int*)d_in[19];
    const int* idx_a = (const int*)d_in[22];
    const int* idx_b = (const int*)d_in[23];
    float* out = (float*)d_out;

    char* ws = (char*)d_ws;
    const size_t MB = 1024 * 1024;
    const size_t KB = 1024;
    float* dinv = (float*)(ws + 0);
    int* cnt = (int*)(ws + 64 * KB);
    int* off = (int*)(ws + 128 * KB);
    int* pos = (int*)(ws + 192 * KB);
    int* csrc = (int*)(ws + 256 * KB);
    float* cw = (float*)(ws + 768 * KB);
    float* util = (float*)(ws + 1280 * KB);
    unsigned char* x8 = (unsigned char*)(ws + 2 * MB);       // 1MB (8192x128 fp8)
    float* h32 = (float*)(ws + 2 * MB);                      // alias, live after layers
    unsigned short* wt_fc1 = (unsigned short*)(ws + 4 * MB);               // 512KB bf16
    unsigned short* wt_fc2p = (unsigned short*)(ws + 4 * MB + 512 * KB);   // 128KB bf16
    unsigned char* wt_in8 = (unsigned char*)(ws + 4 * MB + 640 * KB);      // 64KB
    unsigned char* wt_mid8 = (unsigned char*)(ws + 4 * MB + 704 * KB);     // 256KB
    unsigned char* wt_out8 = (unsigned char*)(ws + 4 * MB + 960 * KB);     // 256KB
    unsigned char* qkv1_8 = (unsigned char*)(ws + 6 * MB);   // 1.5MB (3072x512)
    unsigned char* qkv2_8 = (unsigned char*)(ws + 8 * MB);   // 3MB (3x1024x1024)
    unsigned char* qkv3_8 = (unsigned char*)(ws + 11 * MB);  // 1.5MB (3x512x1024)
    unsigned short* h_b = (unsigned short*)(ws + 13 * MB);   // 8MB bf16 (for fc1)
    unsigned char* h8 = (unsigned char*)(ws + 21 * MB);      // 4MB fp8 (next GCN)
    unsigned char* t1_8 = (unsigned char*)(ws + 25 * MB);    // 24MB (8192x3072)
    unsigned char* t2_8 = (unsigned char*)(ws + 49 * MB);    // 24MB
    unsigned char* xw8 = (unsigned char*)(ws + 73 * MB);     // 4MB fp8
    unsigned char* g8 = (unsigned char*)(ws + 77 * MB);      // 4MB fp8
    unsigned char* q8 = (unsigned char*)(ws + 81 * MB);      // 4MB (q8+4MB=k8, +8MB=vt8)
    unsigned char* k8 = (unsigned char*)(ws + 85 * MB);      // 4MB
    unsigned char* vt8 = (unsigned char*)(ws + 89 * MB);     // 4MB
    float* sc = (float*)(ws + 93 * MB);                      // 4MB fp32
    unsigned char* pbf8 = (unsigned char*)(ws + 97 * MB);    // 1MB
    unsigned short* xb2 = (unsigned short*)(ws + 98 * MB);   // 8MB (ends 106MB)

    // --- weight/activation prep ---
    k_cast8<<<NN * F_IN / 1024, 256, 0, stream>>>(x, x8, NN * F_IN);
    hipMemsetAsync(wt_fc2p, 0, 128 * 512 * sizeof(unsigned short), stream);
    dim3 trb(32, 8);
    k_trz<1><<<dim3(16, 4), trb, 0, stream>>>(w_in, wt_in8, F_IN, DD, 0, 0);
    k_trz<1><<<dim3(16, 16), trb, 0, stream>>>(w_mid, wt_mid8, DD, DD, 0, 0);
    k_trz<1><<<dim3(16, 16), trb, 0, stream>>>(w_out, wt_out8, DD, DD, 0, 0);
    k_trz<0><<<dim3(16, 16), trb, 0, stream>>>(fc1_w, wt_fc1, DD, DD, 0, 0);
    k_trz<0><<<dim3(1, 16), trb, 0, stream>>>(fc2_w, wt_fc2p, DD, 32, 0, 0);
    k_trz<1><<<dim3(32, 16, 3), trb, 0, stream>>>(qkv1_w, qkv1_8, DD, HH, 524288, 524288);
    k_trz<1><<<dim3(32, 32, 3), trb, 0, stream>>>(qkv2_w, qkv2_8, HH, HH, 1048576, 1048576);
    k_trz<1><<<dim3(16, 32, 3), trb, 0, stream>>>(qkv3_w, qkv3_8, HH, DD, 524288, 524288);

    // --- degree + CSR build ---
    k_zero_cnt<<<NN / 256, 256, 0, stream>>>(cnt);
    k_count<<<EE / 256, 256, 0, stream>>>(ei, cnt);
    k_scan<<<1, 1024, 0, stream>>>(cnt, off, pos, dinv);
    k_fill<<<EE / 256, 256, 0, stream>>>(ei, dinv, pos, csrc, cw);

    auto layer = [&](const unsigned char* hin8, const unsigned char* wt8,
                     const float* b, int Kin) {
        // GCN (MX fp8): xw8 = hin @ w, aggregate -> g8 (fp8)
        gemm_mx<0, 10, 1><<<dim3(4, 64), 256, 0, stream>>>(
            hin8, wt8, nullptr, xw8, Kin, Kin, Kin, 512, 512, 0, 0, 0, 0, 0, nullptr);
        gcn_agg<<<NN, 256, 0, stream>>>(xw8, b, off, csrc, cw, dinv, g8);
        // qkv MLP (MX fp8): qkv1 wide M=3072, qkv2 z=3, qkv3 z=3 (v transposed)
        gemm_mx<1, 10, 1><<<dim3(24, 64), 256, 0, stream>>>(
            g8, qkv1_8, qkv1_b, t1_8, 512, 512, 512, 3072, 3072, 0, 0, 0, 0, 0, nullptr);
        gemm_mx<1, 10, 1><<<dim3(8, 64, 3), 256, 0, stream>>>(
            t1_8, qkv2_8, qkv2_b, t2_8, 1024, 3072, 1024, 3072, 1024,
            1024, 1048576, 1024, 1024, 0, nullptr);
        gemm_mx<1, 3, 1><<<dim3(4, 64, 3), 256, 0, stream>>>(
            t2_8, qkv3_8, qkv3_b, q8, 1024, 3072, 1024, 512, 512,
            1024, 524288, 4194304, 512, 0, nullptr);
        // attention (MX fp8): scores (xorb=1), softmax, AV (bf16 + fp8 shadow)
        gemm_mx<3, 0, 0><<<dim3(1, 1, NDOC), 256, 0, stream>>>(
            q8, k8, nullptr, sc, 512, 512, 512, 128, 128,
            65536, 65536, 16384, 0, 1, nullptr);
        softmax128<<<NDOC * 128, 64, 0, stream>>>(sc, pbf8);
        gemm_mx<0, 12, 0><<<dim3(4, 1, NDOC), 256, 0, stream>>>(
            pbf8, vt8, nullptr, h_b, 128, 128, 128, 512, 512,
            16384, 65536, 65536, 0, 1, h8);
    };

    layer(x8, wt_in8, b_in, F_IN);
    layer(h8, wt_mid8, b_mid, DD);
    layer(h8, wt_mid8, b_mid, DD);
    layer(h8, wt_out8, b_out, DD);

    // final FCs (bf16) + pool + pairwise sigmoid
    gemm_mfma<2, 1, 1><<<dim3(4, 64), 256, 0, stream>>>(
        h_b, wt_fc1, fc1_b, xb2, 512, 512, 512, 512, 512, 0, 0, 0, 0, 0);
    gemm_mfma<2, 0, 1><<<dim3(1, 64), 256, 0, stream>>>(
        xb2, wt_fc2p, fc2_b, h32, 512, 512, 512, 32, 32, 0, 0, 0, 0, 0);
    pool_fc3<<<NDOC, 128, 0, stream>>>(h32, fc3_w, fc3_b, util);
    final_out<<<1, 64, 0, stream>>>(util, idx_a, idx_b, out);
}

// Round 10
// 692.120 us; speedup vs baseline: 1.8657x; 1.0243x over previous
//
#include <hip/hip_runtime.h>
#include <math.h>

#define NN 8192
#define NPD 128
#define F_IN 128
#define DD 512
#define HH 1024
#define EE 131072
#define NDOC 64
#define NPAIR 32

typedef __attribute__((ext_vector_type(8))) short bf16x8;
typedef __attribute__((ext_vector_type(4))) float f32x4;
typedef __attribute__((ext_vector_type(4))) int i32x4;
typedef __attribute__((ext_vector_type(8))) int i32x8;
typedef const __attribute__((address_space(1))) void* gas_ptr;
typedef __attribute__((address_space(3))) void* las_ptr;

__device__ __forceinline__ unsigned short f2b(float f) {
    union { float f; unsigned u; } v; v.f = f;
    unsigned r = v.u + 0x7fffu + ((v.u >> 16) & 1u);
    return (unsigned short)(r >> 16);
}
__device__ __forceinline__ unsigned char f2fp8(float f) {
    return (unsigned char)(__builtin_amdgcn_cvt_pk_fp8_f32(f, f, 0, false) & 0xff);
}

// ---------------------------------------------------------------------------
// Degree / CSR construction
// ---------------------------------------------------------------------------
__global__ void k_zero_cnt(int* __restrict__ cnt) {
    int i = blockIdx.x * 256 + threadIdx.x;
    if (i < NN) cnt[i] = 0;
}

__global__ void k_count(const int* __restrict__ ei, int* __restrict__ cnt) {
    int e = blockIdx.x * 256 + threadIdx.x;
    if (e < EE) atomicAdd(&cnt[ei[EE + e]], 1);
}

__global__ void k_scan(const int* __restrict__ cnt, int* __restrict__ off,
                       int* __restrict__ pos, float* __restrict__ dinv) {
    __shared__ int part[1024];
    int t = threadIdx.x;
    int loc[8];
    int s = 0;
    int base = t * 8;
#pragma unroll
    for (int j = 0; j < 8; ++j) {
        int c = cnt[base + j];
        dinv[base + j] = rsqrtf((float)c + 1.0f);
        loc[j] = s;
        s += c;
    }
    part[t] = s;
    __syncthreads();
    for (int st = 1; st < 1024; st <<= 1) {
        int v = (t >= st) ? part[t - st] : 0;
        __syncthreads();
        part[t] += v;
        __syncthreads();
    }
    int pre = (t > 0) ? part[t - 1] : 0;
#pragma unroll
    for (int j = 0; j < 8; ++j) {
        int val = pre + loc[j];
        off[base + j] = val;
        pos[base + j] = val;
    }
    if (t == 1023) off[NN] = part[1023];
}

__global__ void k_fill(const int* __restrict__ ei, const float* __restrict__ dinv,
                       int* __restrict__ pos, int* __restrict__ csr_src,
                       float* __restrict__ csr_w) {
    int e = blockIdx.x * 256 + threadIdx.x;
    if (e >= EE) return;
    int r = ei[e];
    int c = ei[EE + e];
    int p = atomicAdd(&pos[c], 1);
    csr_src[p] = r;
    csr_w[p] = dinv[r] * dinv[c];
}

// ---------------------------------------------------------------------------
__global__ void k_cast8(const float* __restrict__ in, unsigned char* __restrict__ out,
                        int n) {
    int i = (blockIdx.x * 256 + threadIdx.x) * 4;
    if (i < n) {
        float4 v = *(const float4*)(in + i);
        unsigned lo = (unsigned)__builtin_amdgcn_cvt_pk_fp8_f32(v.x, v.y, 0, false) & 0xffffu;
        unsigned hi = (unsigned)__builtin_amdgcn_cvt_pk_fp8_f32(v.z, v.w, 0, false) & 0xffffu;
        *(unsigned*)(out + i) = lo | (hi << 16);
    }
}

// transpose W (K x M fp32) -> Wt (M x K), batched over z. F8: fp8 out else bf16.
template <int F8>
__global__ void k_trz(const float* __restrict__ in, void* __restrict__ outv,
                      int K, int M, long sin, long sout) {
    in += (size_t)blockIdx.z * sin;
    __shared__ float t[32][33];
    int bx = blockIdx.x * 32;
    int by = blockIdx.y * 32;
    int tx = threadIdx.x, ty = threadIdx.y;
    for (int i = ty; i < 32; i += 8)
        t[i][tx] = in[(size_t)(by + i) * M + bx + tx];
    __syncthreads();
    if (F8) {
        unsigned char* out = (unsigned char*)outv + (size_t)blockIdx.z * sout;
        for (int i = ty; i < 32; i += 8)
            out[(size_t)(bx + i) * K + by + tx] = f2fp8(t[tx][i]);
    } else {
        unsigned short* out = (unsigned short*)outv + (size_t)blockIdx.z * sout;
        for (int i = ty; i < 32; i += 8)
            out[(size_t)(bx + i) * K + by + tx] = f2b(t[tx][i]);
    }
}

// ---------------------------------------------------------------------------
// bf16 MFMA GEMM (fc1/fc2): C = act(A @ Bt^T + bias). 128x128 tile, BK=64,
// XOR bank-swizzled LDS. ACT: 0 none,1 relu,2 tanh. OMODE: 0 fp32, 1 bf16
// ---------------------------------------------------------------------------
template <int ACT, int OMODE, int SWZ>
__global__ __launch_bounds__(256) void gemm_mfma(
    const unsigned short* __restrict__ A, const unsigned short* __restrict__ Bt,
    const float* __restrict__ bias, void* __restrict__ Cout,
    int K, int lda, int ldbt, int ldc, int mreal,
    long saz, long sbz, long scz, int sbiasz, int xorb) {
    __shared__ unsigned short As[128 * 64];
    __shared__ unsigned short Bs[128 * 64];

    int bx = blockIdx.x, by = blockIdx.y, bz = blockIdx.z;
    if (SWZ) {
        const int nx = gridDim.x, ny = gridDim.y;
        const int band = ny >> 3;
        int b = (bz * ny + by) * nx + bx;
        const int k = b & 7;
        int s = b >> 3;
        bx = s % nx; s /= nx;
        const int yl = s % band; s /= band;
        bz = s;
        by = k * band + yl;
    }
    const int z = bz;
    A += (size_t)z * saz;
    Bt += (size_t)(z ^ xorb) * sbz;
    if (bias) bias += (size_t)z * sbiasz;

    const int tid = threadIdx.x;
    const int wave = tid >> 6, lane = tid & 63;
    const int m0 = by * 128;
    const int n0 = bx * 128;
    const int wm = (wave & 1) * 64, wn = (wave >> 1) * 64;
    const int lhi = lane >> 4;
    const int llo = lane & 15;
    f32x4 acc[4][4] = {};

    const int srow = lane >> 3;
    const int sseg = (lane & 7) ^ srow;
    const unsigned short* ag = A + (size_t)(m0 + wave * 32 + srow) * lda + sseg * 8;
    const unsigned short* bg = Bt + (size_t)(n0 + wave * 32 + srow) * ldbt + sseg * 8;
    unsigned short* al = As + wave * 2048;
    unsigned short* bl = Bs + wave * 2048;

    const int rxor = (llo & 7) * 8;

    for (int k0 = 0; k0 < K; k0 += 64) {
#pragma unroll
        for (int r = 0; r < 4; ++r) {
            __builtin_amdgcn_global_load_lds((gas_ptr)(ag + k0 + (size_t)r * 8 * lda),
                                             (las_ptr)(al + r * 512), 16, 0, 0);
            __builtin_amdgcn_global_load_lds((gas_ptr)(bg + k0 + (size_t)r * 8 * ldbt),
                                             (las_ptr)(bl + r * 512), 16, 0, 0);
        }
        __syncthreads();
#pragma unroll
        for (int s = 0; s < 2; ++s) {
            const int cofs = ((s * 4 + lhi) * 8) ^ rxor;
            bf16x8 af[4], bf[4];
#pragma unroll
            for (int i = 0; i < 4; ++i) {
                af[i] = *(const bf16x8*)(As + (wm + i * 16 + llo) * 64 + cofs);
                bf[i] = *(const bf16x8*)(Bs + (wn + i * 16 + llo) * 64 + cofs);
            }
#pragma unroll
            for (int i = 0; i < 4; ++i)
#pragma unroll
                for (int j = 0; j < 4; ++j)
                    acc[i][j] = __builtin_amdgcn_mfma_f32_16x16x32_bf16(af[i], bf[j],
                                                                        acc[i][j], 0, 0, 0);
        }
        __syncthreads();
    }

    float* Cf = (float*)Cout + (size_t)z * scz;
    unsigned short* Cb = (unsigned short*)Cout + (size_t)z * scz;
#pragma unroll
    for (int j = 0; j < 4; ++j) {
        const int col = n0 + wn + j * 16 + llo;
        if (col < mreal) {
            const float bv = bias ? bias[col] : 0.f;
#pragma unroll
            for (int i = 0; i < 4; ++i) {
                const int row = m0 + wm + i * 16 + lhi * 4;
#pragma unroll
                for (int r = 0; r < 4; ++r) {
                    float v = acc[i][j][r] + bv;
                    if (ACT == 1) v = fmaxf(v, 0.f);
                    if (ACT == 2) v = tanhf(v);
                    if (OMODE == 0)
                        Cf[(size_t)(row + r) * ldc + col] = v;
                    else
                        Cb[(size_t)(row + r) * ldc + col] = f2b(v);
                }
            }
        }
    }
}

// ---------------------------------------------------------------------------
// MX-scaled fp8 MFMA GEMM (scales=1.0): C = act(A @ Bt^T + bias).
// 128x128 tile, BK=128, XOR bank-swizzled staging (verified r8/r9).
// ACT: 0 none, 1 relu. OMODE: 10 fp8 out; 3 fp8 out, z==2 -> transposed-per-doc
// ---------------------------------------------------------------------------
template <int ACT, int OMODE, int SWZ>
__global__ __launch_bounds__(256) void gemm_mx(
    const unsigned char* __restrict__ A, const unsigned char* __restrict__ Bt,
    const float* __restrict__ bias, void* __restrict__ Cout,
    int K, int lda, int ldbt, int ldc, int mreal,
    long saz, long sbz, long scz, int sbiasz) {
    __shared__ unsigned char As[128 * 128];
    __shared__ unsigned char Bs[128 * 128];

    int bx = blockIdx.x, by = blockIdx.y, bz = blockIdx.z;
    if (SWZ) {
        const int nx = gridDim.x, ny = gridDim.y;
        const int band = ny >> 3;
        int b = (bz * ny + by) * nx + bx;
        const int k = b & 7;
        int s = b >> 3;
        bx = s % nx; s /= nx;
        const int yl = s % band; s /= band;
        bz = s;
        by = k * band + yl;
    }
    const int z = bz;
    A += (size_t)z * saz;
    Bt += (size_t)z * sbz;
    if (bias) bias += (size_t)z * sbiasz;

    const int tid = threadIdx.x;
    const int wave = tid >> 6, lane = tid & 63;
    const int m0 = by * 128;
    const int n0 = bx * 128;
    const int wm = (wave & 1) * 64, wn = (wave >> 1) * 64;
    const int lhi = lane >> 4;
    const int llo = lane & 15;
    f32x4 acc[4][4] = {};

    const int srow = lane >> 3;
    const int sseg = (lane & 7) ^ srow;
    const unsigned char* ag = A + (size_t)(m0 + wave * 32 + srow) * lda + sseg * 16;
    const unsigned char* bg = Bt + (size_t)(n0 + wave * 32 + srow) * ldbt + sseg * 16;
    unsigned char* al = As + wave * 4096;
    unsigned char* bl = Bs + wave * 4096;

    const int rx = llo & 7;
    const int s0 = (2 * lhi) ^ rx;
    const int s1 = (2 * lhi + 1) ^ rx;

    for (int k0 = 0; k0 < K; k0 += 128) {
#pragma unroll
        for (int r = 0; r < 4; ++r) {
            __builtin_amdgcn_global_load_lds((gas_ptr)(ag + k0 + (size_t)r * 8 * lda),
                                             (las_ptr)(al + r * 1024), 16, 0, 0);
            __builtin_amdgcn_global_load_lds((gas_ptr)(bg + k0 + (size_t)r * 8 * ldbt),
                                             (las_ptr)(bl + r * 1024), 16, 0, 0);
        }
        __syncthreads();
        i32x8 af[4], bf[4];
#pragma unroll
        for (int i = 0; i < 4; ++i) {
            const unsigned char* ra = As + (wm + i * 16 + llo) * 128;
            const unsigned char* rb = Bs + (wn + i * 16 + llo) * 128;
            i32x4 a_lo = *(const i32x4*)(ra + s0 * 16);
            i32x4 a_hi = *(const i32x4*)(ra + s1 * 16);
            i32x4 b_lo = *(const i32x4*)(rb + s0 * 16);
            i32x4 b_hi = *(const i32x4*)(rb + s1 * 16);
#pragma unroll
            for (int w = 0; w < 4; ++w) {
                af[i][w] = a_lo[w]; af[i][w + 4] = a_hi[w];
                bf[i][w] = b_lo[w]; bf[i][w + 4] = b_hi[w];
            }
        }
#pragma unroll
        for (int i = 0; i < 4; ++i)
#pragma unroll
            for (int j = 0; j < 4; ++j)
                acc[i][j] = __builtin_amdgcn_mfma_scale_f32_16x16x128_f8f6f4(
                    af[i], bf[j], acc[i][j], 0, 0, 0, 127, 0, 127);
        __syncthreads();
    }

    unsigned char* C8 = (unsigned char*)Cout + (size_t)z * scz;
#pragma unroll
    for (int j = 0; j < 4; ++j) {
        const int col = n0 + wn + j * 16 + llo;
        if (col < mreal) {
            const float bv = bias ? bias[col] : 0.f;
#pragma unroll
            for (int i = 0; i < 4; ++i) {
                const int row = m0 + wm + i * 16 + lhi * 4;
                const int rloc = wm + i * 16 + lhi * 4;
#pragma unroll
                for (int r = 0; r < 4; ++r) {
                    float v = acc[i][j][r] + bv;
                    if (ACT == 1) v = fmaxf(v, 0.f);
                    if (OMODE == 10) {
                        C8[(size_t)(row + r) * ldc + col] = f2fp8(v);
                    } else {  // 3: z<2 normal (q/k), z==2 transposed (vt)
                        if (z < 2)
                            C8[(size_t)(row + r) * ldc + col] = f2fp8(v);
                        else
                            C8[(size_t)by * 65536 + (size_t)col * 128 + rloc + r] = f2fp8(v);
                    }
                }
            }
        }
    }
}

// ---------------------------------------------------------------------------
// Fused cross-doc attention, one block per attention-block z (query doc z,
// key/value doc z^1). Phase 1: S = scale*Q@K^T (MX fp8, C-layout frags).
// Phase 2: in-register softmax (j-reduce + shfl over llo group + 2x128 LDS
// cross-wave combine); P -> LDS fp8, XOR-seg-swizzled for A-frag reads.
// Phase 3: O = P@V over 4 column tiles of V (staged from vt8).
// OUT: 0 -> fp8 h8, 1 -> bf16 h_b.
// ---------------------------------------------------------------------------
template <int OUT>
__global__ __launch_bounds__(256) void attn_fused(
    const unsigned char* __restrict__ q8, const unsigned char* __restrict__ k8,
    const unsigned char* __restrict__ vt8, void* __restrict__ hout) {
    __shared__ unsigned char As[16384];  // Q staging, then P (fp8, swizzled)
    __shared__ unsigned char Bs[16384];  // K staging, then V tiles
    __shared__ float smax[2][128];
    __shared__ float ssum[2][128];

    const int z = blockIdx.x, kd = z ^ 1;
    const int tid = threadIdx.x;
    const int wave = tid >> 6, lane = tid & 63;
    const int wm = (wave & 1) * 64, wn = (wave >> 1) * 64;
    const int lhi = lane >> 4, llo = lane & 15;
    const int srow = lane >> 3;
    const int sseg = (lane & 7) ^ srow;
    const int rx = llo & 7;
    const int s0 = (2 * lhi) ^ rx, s1 = (2 * lhi + 1) ^ rx;

    unsigned char* al = As + wave * 4096;
    unsigned char* bl = Bs + wave * 4096;

    // ---- phase 1: S = Q @ K^T ----
    f32x4 acc[4][4] = {};
    const unsigned char* qg = q8 + (size_t)z * 65536 + (wave * 32 + srow) * 512 + sseg * 16;
    const unsigned char* kg = k8 + (size_t)kd * 65536 + (wave * 32 + srow) * 512 + sseg * 16;
    for (int k0 = 0; k0 < 512; k0 += 128) {
#pragma unroll
        for (int r = 0; r < 4; ++r) {
            __builtin_amdgcn_global_load_lds((gas_ptr)(qg + k0 + r * 8 * 512),
                                             (las_ptr)(al + r * 1024), 16, 0, 0);
            __builtin_amdgcn_global_load_lds((gas_ptr)(kg + k0 + r * 8 * 512),
                                             (las_ptr)(bl + r * 1024), 16, 0, 0);
        }
        __syncthreads();
        i32x8 af[4], bf[4];
#pragma unroll
        for (int i = 0; i < 4; ++i) {
            const unsigned char* ra = As + (wm + i * 16 + llo) * 128;
            const unsigned char* rb = Bs + (wn + i * 16 + llo) * 128;
            i32x4 a_lo = *(const i32x4*)(ra + s0 * 16);
            i32x4 a_hi = *(const i32x4*)(ra + s1 * 16);
            i32x4 b_lo = *(const i32x4*)(rb + s0 * 16);
            i32x4 b_hi = *(const i32x4*)(rb + s1 * 16);
#pragma unroll
            for (int w = 0; w < 4; ++w) {
                af[i][w] = a_lo[w]; af[i][w + 4] = a_hi[w];
                bf[i][w] = b_lo[w]; bf[i][w + 4] = b_hi[w];
            }
        }
#pragma unroll
        for (int i = 0; i < 4; ++i)
#pragma unroll
            for (int j = 0; j < 4; ++j)
                acc[i][j] = __builtin_amdgcn_mfma_scale_f32_16x16x128_f8f6f4(
                    af[i], bf[j], acc[i][j], 0, 0, 0, 127, 0, 127);
        __syncthreads();
    }
    const float scale = 0.044194173824159216f;  // 1/sqrt(512)
#pragma unroll
    for (int i = 0; i < 4; ++i)
#pragma unroll
        for (int j = 0; j < 4; ++j)
            acc[i][j] *= scale;

    // ---- phase 2: softmax over rows (cols split wn=0 / wn=64) ----
    const int half = wn >> 6;
    float pm[4][4];
#pragma unroll
    for (int i = 0; i < 4; ++i)
#pragma unroll
        for (int r = 0; r < 4; ++r) {
            float m = fmaxf(fmaxf(acc[i][0][r], acc[i][1][r]),
                            fmaxf(acc[i][2][r], acc[i][3][r]));
#pragma unroll
            for (int msk = 1; msk < 16; msk <<= 1) m = fmaxf(m, __shfl_xor(m, msk));
            pm[i][r] = m;
        }
    if (llo == 0) {
#pragma unroll
        for (int i = 0; i < 4; ++i)
#pragma unroll
            for (int r = 0; r < 4; ++r)
                smax[half][wm + i * 16 + lhi * 4 + r] = pm[i][r];
    }
    __syncthreads();
    float ps[4][4];
#pragma unroll
    for (int i = 0; i < 4; ++i)
#pragma unroll
        for (int r = 0; r < 4; ++r) {
            const int row = wm + i * 16 + lhi * 4 + r;
            const float m = fmaxf(smax[0][row], smax[1][row]);
            float s = 0.f;
#pragma unroll
            for (int j = 0; j < 4; ++j) {
                acc[i][j][r] = __expf(acc[i][j][r] - m);
                s += acc[i][j][r];
            }
#pragma unroll
            for (int msk = 1; msk < 16; msk <<= 1) s += __shfl_xor(s, msk);
            ps[i][r] = s;
        }
    if (llo == 0) {
#pragma unroll
        for (int i = 0; i < 4; ++i)
#pragma unroll
            for (int r = 0; r < 4; ++r)
                ssum[half][wm + i * 16 + lhi * 4 + r] = ps[i][r];
    }
    __syncthreads();
    // ---- write P (fp8) into As, XOR-seg swizzled: addr = row*128 +
    // ((seg ^ (row&7))<<4) + (col&15), seg = col>>4 ----
#pragma unroll
    for (int i = 0; i < 4; ++i)
#pragma unroll
        for (int r = 0; r < 4; ++r) {
            const int row = wm + i * 16 + lhi * 4 + r;
            const float inv = 1.f / (ssum[0][row] + ssum[1][row]);
#pragma unroll
            for (int j = 0; j < 4; ++j) {
                const int seg = (wn >> 4) + j;
                As[row * 128 + (((seg ^ (row & 7))) << 4) + llo] =
                    f2fp8(acc[i][j][r] * inv);
            }
        }
    __syncthreads();

    // ---- phase 3: O = P @ V, 4 column tiles ----
    i32x8 pf[4];
#pragma unroll
    for (int i = 0; i < 4; ++i) {
        const unsigned char* ra = As + (wm + i * 16 + llo) * 128;
        i32x4 a_lo = *(const i32x4*)(ra + s0 * 16);
        i32x4 a_hi = *(const i32x4*)(ra + s1 * 16);
#pragma unroll
        for (int w = 0; w < 4; ++w) { pf[i][w] = a_lo[w]; pf[i][w + 4] = a_hi[w]; }
    }
    const unsigned char* vg = vt8 + (size_t)kd * 65536;
    for (int t = 0; t < 4; ++t) {
#pragma unroll
        for (int r = 0; r < 4; ++r)
            __builtin_amdgcn_global_load_lds(
                (gas_ptr)(vg + (t * 128 + wave * 32 + srow + r * 8) * 128 + sseg * 16),
                (las_ptr)(bl + r * 1024), 16, 0, 0);
        __syncthreads();
        i32x8 bf[4];
#pragma unroll
        for (int i = 0; i < 4; ++i) {
            const unsigned char* rb = Bs + (wn + i * 16 + llo) * 128;
            i32x4 b_lo = *(const i32x4*)(rb + s0 * 16);
            i32x4 b_hi = *(const i32x4*)(rb + s1 * 16);
#pragma unroll
            for (int w = 0; w < 4; ++w) { bf[i][w] = b_lo[w]; bf[i][w + 4] = b_hi[w]; }
        }
        f32x4 o[4][4] = {};
#pragma unroll
        for (int i = 0; i < 4; ++i)
#pragma unroll
            for (int j = 0; j < 4; ++j)
                o[i][j] = __builtin_amdgcn_mfma_scale_f32_16x16x128_f8f6f4(
                    pf[i], bf[j], o[i][j], 0, 0, 0, 127, 0, 127);
#pragma unroll
        for (int j = 0; j < 4; ++j) {
            const int col = t * 128 + wn + j * 16 + llo;
#pragma unroll
            for (int i = 0; i < 4; ++i) {
                const size_t row = (size_t)z * 128 + wm + i * 16 + lhi * 4;
#pragma unroll
                for (int r = 0; r < 4; ++r) {
                    if (OUT)
                        ((unsigned short*)hout)[(row + r) * 512 + col] = f2b(o[i][j][r]);
                    else
                        ((unsigned char*)hout)[(row + r) * 512 + col] = f2fp8(o[i][j][r]);
                }
            }
        }
        __syncthreads();
    }
}

// ---------------------------------------------------------------------------
// GCN aggregation (fp8 in, fp8 out): out = tanh(sum w*xw[src] + dinv^2*xw + b)
// ---------------------------------------------------------------------------
__global__ __launch_bounds__(256) void gcn_agg(const unsigned char* __restrict__ xw8,
                                               const float* __restrict__ bias,
                                               const int* __restrict__ off,
                                               const int* __restrict__ src,
                                               const float* __restrict__ wgt,
                                               const float* __restrict__ dinv,
                                               unsigned char* __restrict__ out) {
    const int node = blockIdx.x;
    const int t = threadIdx.x;
    const int d0 = 2 * t;
    const int beg = off[node], end = off[node + 1];
    float a0 = 0.f, a1 = 0.f;
    int e = beg;
    for (; e + 1 < end; e += 2) {
        const int s0 = src[e], s1 = src[e + 1];
        const float w0 = wgt[e], w1 = wgt[e + 1];
        const unsigned u0 = *(const unsigned short*)(xw8 + (size_t)s0 * DD + d0);
        const unsigned u1 = *(const unsigned short*)(xw8 + (size_t)s1 * DD + d0);
        auto f0 = __builtin_amdgcn_cvt_pk_f32_fp8(u0, false);
        auto f1 = __builtin_amdgcn_cvt_pk_f32_fp8(u1, false);
        a0 += w0 * f0[0] + w1 * f1[0];
        a1 += w0 * f0[1] + w1 * f1[1];
    }
    if (e < end) {
        const int s0 = src[e];
        const float w0 = wgt[e];
        const unsigned u0 = *(const unsigned short*)(xw8 + (size_t)s0 * DD + d0);
        auto f0 = __builtin_amdgcn_cvt_pk_f32_fp8(u0, false);
        a0 += w0 * f0[0];
        a1 += w0 * f0[1];
    }
    const float ns = dinv[node] * dinv[node];
    const unsigned un = *(const unsigned short*)(xw8 + (size_t)node * DD + d0);
    auto fn = __builtin_amdgcn_cvt_pk_f32_fp8(un, false);
    const float r0 = tanhf(a0 + ns * fn[0] + bias[d0]);
    const float r1 = tanhf(a1 + ns * fn[1] + bias[d0 + 1]);
    unsigned p = (unsigned)__builtin_amdgcn_cvt_pk_fp8_f32(r0, r1, 0, false);
    *(unsigned short*)(out + (size_t)node * DD + d0) = (unsigned short)(p & 0xffff);
}

// ---------------------------------------------------------------------------
__global__ __launch_bounds__(128) void pool_fc3(const float* __restrict__ h32,
                                                const float* __restrict__ w3,
                                                const float* __restrict__ b3,
                                                float* __restrict__ util) {
    const int doc = blockIdx.x;
    const int t = threadIdx.x;
    const float* hp = h32 + (size_t)(doc * 128 + t) * 32;
    float s = 0.f;
#pragma unroll
    for (int j = 0; j < 32; ++j) s += hp[j] * w3[j];
    s += b3[0];
    __shared__ float red[128];
    red[t] = s;
    __syncthreads();
    for (int k = 64; k > 0; k >>= 1) {
        if (t < k) red[t] += red[t + k];
        __syncthreads();
    }
    if (t == 0) util[doc] = red[0] * (1.0f / 128.0f);
}

__global__ void final_out(const float* __restrict__ util, const int* __restrict__ ia,
                          const int* __restrict__ ib, float* __restrict__ out) {
    int i = threadIdx.x;
    if (i < NPAIR) {
        float z = util[ib[i]] - util[ia[i]];
        out[i] = 1.f / (1.f + expf(-z));
    }
}

// ---------------------------------------------------------------------------
extern "C" void kernel_launch(void* const* d_in, const int* in_sizes, int n_in,
                              void* d_out, int out_size, void* d_ws, size_t ws_size,
                              hipStream_t stream) {
    const float* x = (const float*)d_in[0];
    const float* w_in = (const float*)d_in[1];
    const float* b_in = (const float*)d_in[2];
    const float* w_mid = (const float*)d_in[3];
    const float* b_mid = (const float*)d_in[4];
    const float* w_out = (const float*)d_in[5];
    const float* b_out = (const float*)d_in[6];
    const float* fc1_w = (const float*)d_in[7];
    const float* fc1_b = (const float*)d_in[8];
    const float* fc2_w = (const float*)d_in[9];
    const float* fc2_b = (const float*)d_in[10];
    const float* fc3_w = (const float*)d_in[11];
    const float* fc3_b = (const float*)d_in[12];
    const float* qkv1_w = (const float*)d_in[13];
    const float* qkv1_b = (const float*)d_in[14];
    const float* qkv2_w = (const float*)d_in[15];
    const float* qkv2_b = (const float*)d_in[16];
    const float* qkv3_w = (const float*)d_in[17];
    const float* qkv3_b = (const float*)d_in[18];
    const int* ei = (const int*)d_in[19];
    const int* idx_a = (const int*)d_in[22];
    const int* idx_b = (const int*)d_in[23];
    float* out = (float*)d_out;

    char* ws = (char*)d_ws;
    const size_t MB = 1024 * 1024;
    const size_t KB = 1024;
    float* dinv = (float*)(ws + 0);
    int* cnt = (int*)(ws + 64 * KB);
    int* off = (int*)(ws + 128 * KB);
    int* pos = (int*)(ws + 192 * KB);
    int* csrc = (int*)(ws + 256 * KB);
    float* cw = (float*)(ws + 768 * KB);
    float* util = (float*)(ws + 1280 * KB);
    unsigned char* x8 = (unsigned char*)(ws + 2 * MB);       // 1MB (8192x128 fp8)
    float* h32 = (float*)(ws + 2 * MB);                      // alias, live after layers
    unsigned short* wt_fc1 = (unsigned short*)(ws + 4 * MB);               // 512KB bf16
    unsigned short* wt_fc2p = (unsigned short*)(ws + 4 * MB + 512 * KB);   // 128KB bf16
    unsigned char* wt_in8 = (unsigned char*)(ws + 4 * MB + 640 * KB);      // 64KB
    unsigned char* wt_mid8 = (unsigned char*)(ws + 4 * MB + 704 * KB);     // 256KB
    unsigned char* wt_out8 = (unsigned char*)(ws + 4 * MB + 960 * KB);     // 256KB
    unsigned char* qkv1_8 = (unsigned char*)(ws + 6 * MB);   // 1.5MB (3072x512)
    unsigned char* qkv2_8 = (unsigned char*)(ws + 8 * MB);   // 3MB (3x1024x1024)
    unsigned char* qkv3_8 = (unsigned char*)(ws + 11 * MB);  // 1.5MB (3x512x1024)
    unsigned short* h_b = (unsigned short*)(ws + 13 * MB);   // 8MB bf16 (layer 4 only)
    unsigned char* h8 = (unsigned char*)(ws + 21 * MB);      // 4MB fp8 (layers 1-3)
    unsigned char* t1_8 = (unsigned char*)(ws + 25 * MB);    // 24MB (8192x3072)
    unsigned char* t2_8 = (unsigned char*)(ws + 49 * MB);    // 24MB
    unsigned char* xw8 = (unsigned char*)(ws + 73 * MB);     // 4MB fp8
    unsigned char* g8 = (unsigned char*)(ws + 77 * MB);      // 4MB fp8
    unsigned char* q8 = (unsigned char*)(ws + 81 * MB);      // 4MB
    unsigned char* k8 = (unsigned char*)(ws + 85 * MB);      // 4MB (q8+4MB)
    unsigned char* vt8 = (unsigned char*)(ws + 89 * MB);     // 4MB (q8+8MB)
    unsigned short* xb2 = (unsigned short*)(ws + 93 * MB);   // 8MB (ends 101MB)

    // --- weight/activation prep ---
    k_cast8<<<NN * F_IN / 1024, 256, 0, stream>>>(x, x8, NN * F_IN);
    hipMemsetAsync(wt_fc2p, 0, 128 * 512 * sizeof(unsigned short), stream);
    dim3 trb(32, 8);
    k_trz<1><<<dim3(16, 4), trb, 0, stream>>>(w_in, wt_in8, F_IN, DD, 0, 0);
    k_trz<1><<<dim3(16, 16), trb, 0, stream>>>(w_mid, wt_mid8, DD, DD, 0, 0);
    k_trz<1><<<dim3(16, 16), trb, 0, stream>>>(w_out, wt_out8, DD, DD, 0, 0);
    k_trz<0><<<dim3(16, 16), trb, 0, stream>>>(fc1_w, wt_fc1, DD, DD, 0, 0);
    k_trz<0><<<dim3(1, 16), trb, 0, stream>>>(fc2_w, wt_fc2p, DD, 32, 0, 0);
    k_trz<1><<<dim3(32, 16, 3), trb, 0, stream>>>(qkv1_w, qkv1_8, DD, HH, 524288, 524288);
    k_trz<1><<<dim3(32, 32, 3), trb, 0, stream>>>(qkv2_w, qkv2_8, HH, HH, 1048576, 1048576);
    k_trz<1><<<dim3(16, 32, 3), trb, 0, stream>>>(qkv3_w, qkv3_8, HH, DD, 524288, 524288);

    // --- degree + CSR build ---
    k_zero_cnt<<<NN / 256, 256, 0, stream>>>(cnt);
    k_count<<<EE / 256, 256, 0, stream>>>(ei, cnt);
    k_scan<<<1, 1024, 0, stream>>>(cnt, off, pos, dinv);
    k_fill<<<EE / 256, 256, 0, stream>>>(ei, dinv, pos, csrc, cw);

    auto layer = [&](const unsigned char* hin8, const unsigned char* wt8,
                     const float* b, int Kin, bool last) {
        // GCN (MX fp8): xw8 = hin @ w, aggregate -> g8 (fp8)
        gemm_mx<0, 10, 1><<<dim3(4, 64), 256, 0, stream>>>(
            hin8, wt8, nullptr, xw8, Kin, Kin, Kin, 512, 512, 0, 0, 0, 0);
        gcn_agg<<<NN, 256, 0, stream>>>(xw8, b, off, csrc, cw, dinv, g8);
        // qkv MLP (MX fp8): qkv1 wide M=3072, qkv2 z=3, qkv3 z=3 (v transposed)
        gemm_mx<1, 10, 1><<<dim3(24, 64), 256, 0, stream>>>(
            g8, qkv1_8, qkv1_b, t1_8, 512, 512, 512, 3072, 3072, 0, 0, 0, 0);
        gemm_mx<1, 10, 1><<<dim3(8, 64, 3), 256, 0, stream>>>(
            t1_8, qkv2_8, qkv2_b, t2_8, 1024, 3072, 1024, 3072, 1024,
            1024, 1048576, 1024, 1024);
        gemm_mx<1, 3, 1><<<dim3(4, 64, 3), 256, 0, stream>>>(
            t2_8, qkv3_8, qkv3_b, q8, 1024, 3072, 1024, 512, 512,
            1024, 524288, 4194304, 512);
        // fused attention: scores + softmax + AV
        if (last)
            attn_fused<1><<<NDOC, 256, 0, stream>>>(q8, k8, vt8, h_b);
        else
            attn_fused<0><<<NDOC, 256, 0, stream>>>(q8, k8, vt8, h8);
    };

    layer(x8, wt_in8, b_in, F_IN, false);
    layer(h8, wt_mid8, b_mid, DD, false);
    layer(h8, wt_mid8, b_mid, DD, false);
    layer(h8, wt_out8, b_out, DD, true);

    // final FCs (bf16) + pool + pairwise sigmoid
    gemm_mfma<2, 1, 1><<<dim3(4, 64), 256, 0, stream>>>(
        h_b, wt_fc1, fc1_b, xb2, 512, 512, 512, 512, 512, 0, 0, 0, 0, 0);
    gemm_mfma<2, 0, 1><<<dim3(1, 64), 256, 0, stream>>>(
        xb2, wt_fc2p, fc2_b, h32, 512, 512, 512, 32, 32, 0, 0, 0, 0, 0);
    pool_fc3<<<NDOC, 128, 0, stream>>>(h32, fc3_w, fc3_b, util);
    final_out<<<1, 64, 0, stream>>>(util, idx_a, idx_b, out);
}

// Round 11
// 647.509 us; speedup vs baseline: 1.9942x; 1.0689x over previous
//
#include <hip/hip_runtime.h>
#include <math.h>

#define NN 8192
#define NPD 128
#define F_IN 128
#define DD 512
#define HH 1024
#define EE 131072
#define NDOC 64
#define NPAIR 32

typedef __attribute__((ext_vector_type(4))) float f32x4;
typedef __attribute__((ext_vector_type(4))) int i32x4;
typedef __attribute__((ext_vector_type(8))) int i32x8;
typedef const __attribute__((address_space(1))) void* gas_ptr;
typedef __attribute__((address_space(3))) void* las_ptr;

__device__ __forceinline__ unsigned char f2fp8(float f) {
    return (unsigned char)(__builtin_amdgcn_cvt_pk_fp8_f32(f, f, 0, false) & 0xff);
}

// ---------------------------------------------------------------------------
// Fused prep: x cast to fp8 (1024 blocks) + cnt zero (32) + all weight
// transposes K x M fp32 -> M x K fp8 (7040 blocks, job table).
// fc2 job pads M 32->128 with zeros (read-guarded).
// ---------------------------------------------------------------------------
__global__ __launch_bounds__(256) void k_prep(
    const float* __restrict__ x, unsigned char* __restrict__ x8,
    int* __restrict__ cnt,
    const float* __restrict__ w_in, unsigned char* __restrict__ wt_in8,
    const float* __restrict__ w_mid, unsigned char* __restrict__ wt_mid8,
    const float* __restrict__ w_out, unsigned char* __restrict__ wt_out8,
    const float* __restrict__ fc1_w, unsigned char* __restrict__ wt_fc18,
    const float* __restrict__ fc2_w, unsigned char* __restrict__ wt_fc2p8,
    const float* __restrict__ qkv1_w, unsigned char* __restrict__ qkv1_8,
    const float* __restrict__ qkv2_w, unsigned char* __restrict__ qkv2_8,
    const float* __restrict__ qkv3_w, unsigned char* __restrict__ qkv3_8) {
    int b = blockIdx.x;
    const int tid = threadIdx.x;
    if (b < 1024) {  // cast x -> fp8
        int i = (b * 256 + tid) * 4;
        float4 v = *(const float4*)(x + i);
        unsigned lo = (unsigned)__builtin_amdgcn_cvt_pk_fp8_f32(v.x, v.y, 0, false) & 0xffffu;
        unsigned hi = (unsigned)__builtin_amdgcn_cvt_pk_fp8_f32(v.z, v.w, 0, false) & 0xffffu;
        *(unsigned*)(x8 + i) = lo | (hi << 16);
        return;
    }
    b -= 1024;
    if (b < 32) { cnt[b * 256 + tid] = 0; return; }
    b -= 32;
    const float* src; unsigned char* dst;
    int K, M, nx, ny, mreal; long sw = 0;
    if (b < 64)        {          src = w_in;   dst = wt_in8;   K = 128;  M = 512;  nx = 16; ny = 4;  mreal = 512; }
    else if (b < 320)  { b -= 64;   src = w_mid;  dst = wt_mid8;  K = 512;  M = 512;  nx = 16; ny = 16; mreal = 512; }
    else if (b < 576)  { b -= 320;  src = w_out;  dst = wt_out8;  K = 512;  M = 512;  nx = 16; ny = 16; mreal = 512; }
    else if (b < 832)  { b -= 576;  src = fc1_w;  dst = wt_fc18;  K = 512;  M = 512;  nx = 16; ny = 16; mreal = 512; }
    else if (b < 896)  { b -= 832;  src = fc2_w;  dst = wt_fc2p8; K = 512;  M = 32;   nx = 4;  ny = 16; mreal = 32; }
    else if (b < 2432) { b -= 896;  src = qkv1_w; dst = qkv1_8;   K = 512;  M = 1024; nx = 32; ny = 16; mreal = 1024; sw = 524288; }
    else if (b < 5504) { b -= 2432; src = qkv2_w; dst = qkv2_8;   K = 1024; M = 1024; nx = 32; ny = 32; mreal = 1024; sw = 1048576; }
    else               { b -= 5504; src = qkv3_w; dst = qkv3_8;   K = 1024; M = 512;  nx = 16; ny = 32; mreal = 512;  sw = 524288; }
    const int bx = (b % nx) * 32;
    const int rest = b / nx;
    const int by = (rest % ny) * 32;
    const int z = rest / ny;
    src += (size_t)z * sw;
    dst += (size_t)z * sw;
    __shared__ float t[32][33];
    const int tx = tid & 31, ty = tid >> 5;
    for (int i = ty; i < 32; i += 8)
        t[i][tx] = (bx + tx < mreal) ? src[(size_t)(by + i) * M + bx + tx] : 0.f;
    __syncthreads();
    for (int i = ty; i < 32; i += 8)
        dst[(size_t)(bx + i) * K + by + tx] = f2fp8(t[tx][i]);
}

// ---------------------------------------------------------------------------
// Degree / CSR construction
// ---------------------------------------------------------------------------
__global__ void k_count(const int* __restrict__ ei, int* __restrict__ cnt) {
    int e = blockIdx.x * 256 + threadIdx.x;
    if (e < EE) atomicAdd(&cnt[ei[EE + e]], 1);
}

__global__ void k_scan(const int* __restrict__ cnt, int* __restrict__ off,
                       int* __restrict__ pos, float* __restrict__ dinv) {
    __shared__ int part[1024];
    int t = threadIdx.x;
    int loc[8];
    int s = 0;
    int base = t * 8;
#pragma unroll
    for (int j = 0; j < 8; ++j) {
        int c = cnt[base + j];
        dinv[base + j] = rsqrtf((float)c + 1.0f);
        loc[j] = s;
        s += c;
    }
    part[t] = s;
    __syncthreads();
    for (int st = 1; st < 1024; st <<= 1) {
        int v = (t >= st) ? part[t - st] : 0;
        __syncthreads();
        part[t] += v;
        __syncthreads();
    }
    int pre = (t > 0) ? part[t - 1] : 0;
#pragma unroll
    for (int j = 0; j < 8; ++j) {
        int val = pre + loc[j];
        off[base + j] = val;
        pos[base + j] = val;
    }
    if (t == 1023) off[NN] = part[1023];
}

__global__ void k_fill(const int* __restrict__ ei, const float* __restrict__ dinv,
                       int* __restrict__ pos, int* __restrict__ csr_src,
                       float* __restrict__ csr_w) {
    int e = blockIdx.x * 256 + threadIdx.x;
    if (e >= EE) return;
    int r = ei[e];
    int c = ei[EE + e];
    int p = atomicAdd(&pos[c], 1);
    csr_src[p] = r;
    csr_w[p] = dinv[r] * dinv[c];
}

// ---------------------------------------------------------------------------
// MX-scaled fp8 MFMA GEMM (scales=1.0): C = act(A @ Bt^T + bias).
// 128x128 tile, BK=128, XOR bank-swizzled staging (verified r8-r10).
// ACT: 0 none, 1 relu, 2 tanh.
// OMODE: 0 fp32 out; 10 fp8 out; 3 fp8 out, z==2 -> transposed-per-doc (vt)
// ---------------------------------------------------------------------------
template <int ACT, int OMODE, int SWZ>
__global__ __launch_bounds__(256) void gemm_mx(
    const unsigned char* __restrict__ A, const unsigned char* __restrict__ Bt,
    const float* __restrict__ bias, void* __restrict__ Cout,
    int K, int lda, int ldbt, int ldc, int mreal,
    long saz, long sbz, long scz, int sbiasz) {
    __shared__ unsigned char As[128 * 128];
    __shared__ unsigned char Bs[128 * 128];

    int bx = blockIdx.x, by = blockIdx.y, bz = blockIdx.z;
    if (SWZ) {
        const int nx = gridDim.x, ny = gridDim.y;
        const int band = ny >> 3;
        int b = (bz * ny + by) * nx + bx;
        const int k = b & 7;
        int s = b >> 3;
        bx = s % nx; s /= nx;
        const int yl = s % band; s /= band;
        bz = s;
        by = k * band + yl;
    }
    const int z = bz;
    A += (size_t)z * saz;
    Bt += (size_t)z * sbz;
    if (bias) bias += (size_t)z * sbiasz;

    const int tid = threadIdx.x;
    const int wave = tid >> 6, lane = tid & 63;
    const int m0 = by * 128;
    const int n0 = bx * 128;
    const int wm = (wave & 1) * 64, wn = (wave >> 1) * 64;
    const int lhi = lane >> 4;
    const int llo = lane & 15;
    f32x4 acc[4][4] = {};

    const int srow = lane >> 3;
    const int sseg = (lane & 7) ^ srow;
    const unsigned char* ag = A + (size_t)(m0 + wave * 32 + srow) * lda + sseg * 16;
    const unsigned char* bg = Bt + (size_t)(n0 + wave * 32 + srow) * ldbt + sseg * 16;
    unsigned char* al = As + wave * 4096;
    unsigned char* bl = Bs + wave * 4096;

    const int rx = llo & 7;
    const int s0 = (2 * lhi) ^ rx;
    const int s1 = (2 * lhi + 1) ^ rx;

    for (int k0 = 0; k0 < K; k0 += 128) {
#pragma unroll
        for (int r = 0; r < 4; ++r) {
            __builtin_amdgcn_global_load_lds((gas_ptr)(ag + k0 + (size_t)r * 8 * lda),
                                             (las_ptr)(al + r * 1024), 16, 0, 0);
            __builtin_amdgcn_global_load_lds((gas_ptr)(bg + k0 + (size_t)r * 8 * ldbt),
                                             (las_ptr)(bl + r * 1024), 16, 0, 0);
        }
        __syncthreads();
        i32x8 af[4], bf[4];
#pragma unroll
        for (int i = 0; i < 4; ++i) {
            const unsigned char* ra = As + (wm + i * 16 + llo) * 128;
            const unsigned char* rb = Bs + (wn + i * 16 + llo) * 128;
            i32x4 a_lo = *(const i32x4*)(ra + s0 * 16);
            i32x4 a_hi = *(const i32x4*)(ra + s1 * 16);
            i32x4 b_lo = *(const i32x4*)(rb + s0 * 16);
            i32x4 b_hi = *(const i32x4*)(rb + s1 * 16);
#pragma unroll
            for (int w = 0; w < 4; ++w) {
                af[i][w] = a_lo[w]; af[i][w + 4] = a_hi[w];
                bf[i][w] = b_lo[w]; bf[i][w + 4] = b_hi[w];
            }
        }
#pragma unroll
        for (int i = 0; i < 4; ++i)
#pragma unroll
            for (int j = 0; j < 4; ++j)
                acc[i][j] = __builtin_amdgcn_mfma_scale_f32_16x16x128_f8f6f4(
                    af[i], bf[j], acc[i][j], 0, 0, 0, 127, 0, 127);
        __syncthreads();
    }

    float* Cf = (float*)Cout + (size_t)z * scz;
    unsigned char* C8 = (unsigned char*)Cout + (size_t)z * scz;
#pragma unroll
    for (int j = 0; j < 4; ++j) {
        const int col = n0 + wn + j * 16 + llo;
        if (col < mreal) {
            const float bv = bias ? bias[col] : 0.f;
#pragma unroll
            for (int i = 0; i < 4; ++i) {
                const int row = m0 + wm + i * 16 + lhi * 4;
                const int rloc = wm + i * 16 + lhi * 4;
#pragma unroll
                for (int r = 0; r < 4; ++r) {
                    float v = acc[i][j][r] + bv;
                    if (ACT == 1) v = fmaxf(v, 0.f);
                    if (ACT == 2) v = tanhf(v);
                    if (OMODE == 0) {
                        Cf[(size_t)(row + r) * ldc + col] = v;
                    } else if (OMODE == 10) {
                        C8[(size_t)(row + r) * ldc + col] = f2fp8(v);
                    } else {  // 3: z<2 normal (q/k), z==2 transposed (vt)
                        if (z < 2)
                            C8[(size_t)(row + r) * ldc + col] = f2fp8(v);
                        else
                            C8[(size_t)by * 65536 + (size_t)col * 128 + rloc + r] = f2fp8(v);
                    }
                }
            }
        }
    }
}

// ---------------------------------------------------------------------------
// Fused cross-doc attention (verified r10), fp8 output.
// ---------------------------------------------------------------------------
__global__ __launch_bounds__(256) void attn_fused(
    const unsigned char* __restrict__ q8, const unsigned char* __restrict__ k8,
    const unsigned char* __restrict__ vt8, unsigned char* __restrict__ hout) {
    __shared__ unsigned char As[16384];  // Q staging, then P (fp8, swizzled)
    __shared__ unsigned char Bs[16384];  // K staging, then V tiles
    __shared__ float smax[2][128];
    __shared__ float ssum[2][128];

    const int z = blockIdx.x, kd = z ^ 1;
    const int tid = threadIdx.x;
    const int wave = tid >> 6, lane = tid & 63;
    const int wm = (wave & 1) * 64, wn = (wave >> 1) * 64;
    const int lhi = lane >> 4, llo = lane & 15;
    const int srow = lane >> 3;
    const int sseg = (lane & 7) ^ srow;
    const int rx = llo & 7;
    const int s0 = (2 * lhi) ^ rx, s1 = (2 * lhi + 1) ^ rx;

    unsigned char* al = As + wave * 4096;
    unsigned char* bl = Bs + wave * 4096;

    // ---- phase 1: S = Q @ K^T ----
    f32x4 acc[4][4] = {};
    const unsigned char* qg = q8 + (size_t)z * 65536 + (wave * 32 + srow) * 512 + sseg * 16;
    const unsigned char* kg = k8 + (size_t)kd * 65536 + (wave * 32 + srow) * 512 + sseg * 16;
    for (int k0 = 0; k0 < 512; k0 += 128) {
#pragma unroll
        for (int r = 0; r < 4; ++r) {
            __builtin_amdgcn_global_load_lds((gas_ptr)(qg + k0 + r * 8 * 512),
                                             (las_ptr)(al + r * 1024), 16, 0, 0);
            __builtin_amdgcn_global_load_lds((gas_ptr)(kg + k0 + r * 8 * 512),
                                             (las_ptr)(bl + r * 1024), 16, 0, 0);
        }
        __syncthreads();
        i32x8 af[4], bf[4];
#pragma unroll
        for (int i = 0; i < 4; ++i) {
            const unsigned char* ra = As + (wm + i * 16 + llo) * 128;
            const unsigned char* rb = Bs + (wn + i * 16 + llo) * 128;
            i32x4 a_lo = *(const i32x4*)(ra + s0 * 16);
            i32x4 a_hi = *(const i32x4*)(ra + s1 * 16);
            i32x4 b_lo = *(const i32x4*)(rb + s0 * 16);
            i32x4 b_hi = *(const i32x4*)(rb + s1 * 16);
#pragma unroll
            for (int w = 0; w < 4; ++w) {
                af[i][w] = a_lo[w]; af[i][w + 4] = a_hi[w];
                bf[i][w] = b_lo[w]; bf[i][w + 4] = b_hi[w];
            }
        }
#pragma unroll
        for (int i = 0; i < 4; ++i)
#pragma unroll
            for (int j = 0; j < 4; ++j)
                acc[i][j] = __builtin_amdgcn_mfma_scale_f32_16x16x128_f8f6f4(
                    af[i], bf[j], acc[i][j], 0, 0, 0, 127, 0, 127);
        __syncthreads();
    }
    const float scale = 0.044194173824159216f;  // 1/sqrt(512)
#pragma unroll
    for (int i = 0; i < 4; ++i)
#pragma unroll
        for (int j = 0; j < 4; ++j)
            acc[i][j] *= scale;

    // ---- phase 2: softmax over rows (cols split wn=0 / wn=64) ----
    const int half = wn >> 6;
    float pm[4][4];
#pragma unroll
    for (int i = 0; i < 4; ++i)
#pragma unroll
        for (int r = 0; r < 4; ++r) {
            float m = fmaxf(fmaxf(acc[i][0][r], acc[i][1][r]),
                            fmaxf(acc[i][2][r], acc[i][3][r]));
#pragma unroll
            for (int msk = 1; msk < 16; msk <<= 1) m = fmaxf(m, __shfl_xor(m, msk));
            pm[i][r] = m;
        }
    if (llo == 0) {
#pragma unroll
        for (int i = 0; i < 4; ++i)
#pragma unroll
            for (int r = 0; r < 4; ++r)
                smax[half][wm + i * 16 + lhi * 4 + r] = pm[i][r];
    }
    __syncthreads();
    float ps[4][4];
#pragma unroll
    for (int i = 0; i < 4; ++i)
#pragma unroll
        for (int r = 0; r < 4; ++r) {
            const int row = wm + i * 16 + lhi * 4 + r;
            const float m = fmaxf(smax[0][row], smax[1][row]);
            float s = 0.f;
#pragma unroll
            for (int j = 0; j < 4; ++j) {
                acc[i][j][r] = __expf(acc[i][j][r] - m);
                s += acc[i][j][r];
            }
#pragma unroll
            for (int msk = 1; msk < 16; msk <<= 1) s += __shfl_xor(s, msk);
            ps[i][r] = s;
        }
    if (llo == 0) {
#pragma unroll
        for (int i = 0; i < 4; ++i)
#pragma unroll
            for (int r = 0; r < 4; ++r)
                ssum[half][wm + i * 16 + lhi * 4 + r] = ps[i][r];
    }
    __syncthreads();
    // write P (fp8) into As, XOR-seg swizzled
#pragma unroll
    for (int i = 0; i < 4; ++i)
#pragma unroll
        for (int r = 0; r < 4; ++r) {
            const int row = wm + i * 16 + lhi * 4 + r;
            const float inv = 1.f / (ssum[0][row] + ssum[1][row]);
#pragma unroll
            for (int j = 0; j < 4; ++j) {
                const int seg = (wn >> 4) + j;
                As[row * 128 + (((seg ^ (row & 7))) << 4) + llo] =
                    f2fp8(acc[i][j][r] * inv);
            }
        }
    __syncthreads();

    // ---- phase 3: O = P @ V, 4 column tiles ----
    i32x8 pf[4];
#pragma unroll
    for (int i = 0; i < 4; ++i) {
        const unsigned char* ra = As + (wm + i * 16 + llo) * 128;
        i32x4 a_lo = *(const i32x4*)(ra + s0 * 16);
        i32x4 a_hi = *(const i32x4*)(ra + s1 * 16);
#pragma unroll
        for (int w = 0; w < 4; ++w) { pf[i][w] = a_lo[w]; pf[i][w + 4] = a_hi[w]; }
    }
    const unsigned char* vg = vt8 + (size_t)kd * 65536;
    for (int t = 0; t < 4; ++t) {
#pragma unroll
        for (int r = 0; r < 4; ++r)
            __builtin_amdgcn_global_load_lds(
                (gas_ptr)(vg + (t * 128 + wave * 32 + srow + r * 8) * 128 + sseg * 16),
                (las_ptr)(bl + r * 1024), 16, 0, 0);
        __syncthreads();
        i32x8 bf[4];
#pragma unroll
        for (int i = 0; i < 4; ++i) {
            const unsigned char* rb = Bs + (wn + i * 16 + llo) * 128;
            i32x4 b_lo = *(const i32x4*)(rb + s0 * 16);
            i32x4 b_hi = *(const i32x4*)(rb + s1 * 16);
#pragma unroll
            for (int w = 0; w < 4; ++w) { bf[i][w] = b_lo[w]; bf[i][w + 4] = b_hi[w]; }
        }
        f32x4 o[4][4] = {};
#pragma unroll
        for (int i = 0; i < 4; ++i)
#pragma unroll
            for (int j = 0; j < 4; ++j)
                o[i][j] = __builtin_amdgcn_mfma_scale_f32_16x16x128_f8f6f4(
                    pf[i], bf[j], o[i][j], 0, 0, 0, 127, 0, 127);
#pragma unroll
        for (int j = 0; j < 4; ++j) {
            const int col = t * 128 + wn + j * 16 + llo;
#pragma unroll
            for (int i = 0; i < 4; ++i) {
                const size_t row = (size_t)z * 128 + wm + i * 16 + lhi * 4;
#pragma unroll
                for (int r = 0; r < 4; ++r)
                    hout[(row + r) * 512 + col] = f2fp8(o[i][j][r]);
            }
        }
        __syncthreads();
    }
}

// ---------------------------------------------------------------------------
// GCN aggregation (fp8 in/out), 4-edge unroll for gather-latency MLP
// ---------------------------------------------------------------------------
__global__ __launch_bounds__(256) void gcn_agg(const unsigned char* __restrict__ xw8,
                                               const float* __restrict__ bias,
                                               const int* __restrict__ off,
                                               const int* __restrict__ src,
                                               const float* __restrict__ wgt,
                                               const float* __restrict__ dinv,
                                               unsigned char* __restrict__ out) {
    const int node = blockIdx.x;
    const int t = threadIdx.x;
    const int d0 = 2 * t;
    const int beg = off[node], end = off[node + 1];
    float a0 = 0.f, a1 = 0.f;
    int e = beg;
    for (; e + 3 < end; e += 4) {
        const int s0 = src[e], s1 = src[e + 1], s2 = src[e + 2], s3 = src[e + 3];
        const float w0 = wgt[e], w1 = wgt[e + 1], w2 = wgt[e + 2], w3 = wgt[e + 3];
        const unsigned u0 = *(const unsigned short*)(xw8 + (size_t)s0 * DD + d0);
        const unsigned u1 = *(const unsigned short*)(xw8 + (size_t)s1 * DD + d0);
        const unsigned u2 = *(const unsigned short*)(xw8 + (size_t)s2 * DD + d0);
        const unsigned u3 = *(const unsigned short*)(xw8 + (size_t)s3 * DD + d0);
        auto f0 = __builtin_amdgcn_cvt_pk_f32_fp8(u0, false);
        auto f1 = __builtin_amdgcn_cvt_pk_f32_fp8(u1, false);
        auto f2 = __builtin_amdgcn_cvt_pk_f32_fp8(u2, false);
        auto f3 = __builtin_amdgcn_cvt_pk_f32_fp8(u3, false);
        a0 += w0 * f0[0] + w1 * f1[0] + w2 * f2[0] + w3 * f3[0];
        a1 += w0 * f0[1] + w1 * f1[1] + w2 * f2[1] + w3 * f3[1];
    }
    for (; e < end; ++e) {
        const int s0 = src[e];
        const float w0 = wgt[e];
        const unsigned u0 = *(const unsigned short*)(xw8 + (size_t)s0 * DD + d0);
        auto f0 = __builtin_amdgcn_cvt_pk_f32_fp8(u0, false);
        a0 += w0 * f0[0];
        a1 += w0 * f0[1];
    }
    const float ns = dinv[node] * dinv[node];
    const unsigned un = *(const unsigned short*)(xw8 + (size_t)node * DD + d0);
    auto fn = __builtin_amdgcn_cvt_pk_f32_fp8(un, false);
    const float r0 = tanhf(a0 + ns * fn[0] + bias[d0]);
    const float r1 = tanhf(a1 + ns * fn[1] + bias[d0 + 1]);
    unsigned p = (unsigned)__builtin_amdgcn_cvt_pk_fp8_f32(r0, r1, 0, false);
    *(unsigned short*)(out + (size_t)node * DD + d0) = (unsigned short)(p & 0xffff);
}

// ---------------------------------------------------------------------------
__global__ __launch_bounds__(128) void pool_fc3(const float* __restrict__ h32,
                                                const float* __restrict__ w3,
                                                const float* __restrict__ b3,
                                                float* __restrict__ util) {
    const int doc = blockIdx.x;
    const int t = threadIdx.x;
    const float* hp = h32 + (size_t)(doc * 128 + t) * 32;
    float s = 0.f;
#pragma unroll
    for (int j = 0; j < 32; ++j) s += hp[j] * w3[j];
    s += b3[0];
    __shared__ float red[128];
    red[t] = s;
    __syncthreads();
    for (int k = 64; k > 0; k >>= 1) {
        if (t < k) red[t] += red[t + k];
        __syncthreads();
    }
    if (t == 0) util[doc] = red[0] * (1.0f / 128.0f);
}

__global__ void final_out(const float* __restrict__ util, const int* __restrict__ ia,
                          const int* __restrict__ ib, float* __restrict__ out) {
    int i = threadIdx.x;
    if (i < NPAIR) {
        float z = util[ib[i]] - util[ia[i]];
        out[i] = 1.f / (1.f + expf(-z));
    }
}

// ---------------------------------------------------------------------------
extern "C" void kernel_launch(void* const* d_in, const int* in_sizes, int n_in,
                              void* d_out, int out_size, void* d_ws, size_t ws_size,
                              hipStream_t stream) {
    const float* x = (const float*)d_in[0];
    const float* w_in = (const float*)d_in[1];
    const float* b_in = (const float*)d_in[2];
    const float* w_mid = (const float*)d_in[3];
    const float* b_mid = (const float*)d_in[4];
    const float* w_out = (const float*)d_in[5];
    const float* b_out = (const float*)d_in[6];
    const float* fc1_w = (const float*)d_in[7];
    const float* fc1_b = (const float*)d_in[8];
    const float* fc2_w = (const float*)d_in[9];
    const float* fc2_b = (const float*)d_in[10];
    const float* fc3_w = (const float*)d_in[11];
    const float* fc3_b = (const float*)d_in[12];
    const float* qkv1_w = (const float*)d_in[13];
    const float* qkv1_b = (const float*)d_in[14];
    const float* qkv2_w = (const float*)d_in[15];
    const float* qkv2_b = (const float*)d_in[16];
    const float* qkv3_w = (const float*)d_in[17];
    const float* qkv3_b = (const float*)d_in[18];
    const int* ei = (const int*)d_in[19];
    const int* idx_a = (const int*)d_in[22];
    const int* idx_b = (const int*)d_in[23];
    float* out = (float*)d_out;

    char* ws = (char*)d_ws;
    const size_t MB = 1024 * 1024;
    const size_t KB = 1024;
    float* dinv = (float*)(ws + 0);
    int* cnt = (int*)(ws + 64 * KB);
    int* off = (int*)(ws + 128 * KB);
    int* pos = (int*)(ws + 192 * KB);
    int* csrc = (int*)(ws + 256 * KB);
    float* cw = (float*)(ws + 768 * KB);
    float* util = (float*)(ws + 1280 * KB);
    unsigned char* x8 = (unsigned char*)(ws + 2 * MB);       // 1MB fp8 (layer 1 only)
    float* h32 = (float*)(ws + 2 * MB);                      // 1MB alias, end of net
    unsigned char* wt_in8 = (unsigned char*)(ws + 4 * MB);                 // 64KB
    unsigned char* wt_mid8 = (unsigned char*)(ws + 4 * MB + 64 * KB);      // 256KB
    unsigned char* wt_out8 = (unsigned char*)(ws + 4 * MB + 320 * KB);     // 256KB
    unsigned char* wt_fc18 = (unsigned char*)(ws + 4 * MB + 576 * KB);     // 256KB
    unsigned char* wt_fc2p8 = (unsigned char*)(ws + 4 * MB + 832 * KB);    // 64KB padded
    unsigned char* qkv1_8 = (unsigned char*)(ws + 6 * MB);   // 1.5MB
    unsigned char* qkv2_8 = (unsigned char*)(ws + 8 * MB);   // 3MB
    unsigned char* qkv3_8 = (unsigned char*)(ws + 11 * MB);  // 1.5MB
    unsigned char* h8 = (unsigned char*)(ws + 21 * MB);      // 4MB fp8
    unsigned char* t1_8 = (unsigned char*)(ws + 25 * MB);    // 24MB
    unsigned char* t2_8 = (unsigned char*)(ws + 49 * MB);    // 24MB
    unsigned char* xw8 = (unsigned char*)(ws + 73 * MB);     // 4MB
    unsigned char* g8 = (unsigned char*)(ws + 77 * MB);      // 4MB
    unsigned char* q8 = (unsigned char*)(ws + 81 * MB);      // 4MB
    unsigned char* k8 = (unsigned char*)(ws + 85 * MB);      // 4MB (q8+4MB)
    unsigned char* vt8 = (unsigned char*)(ws + 89 * MB);     // 4MB (q8+8MB)
    unsigned char* x2_8 = (unsigned char*)(ws + 93 * MB);    // 4MB (ends 97MB)

    // --- fused prep (cast + cnt zero + all weight transposes) ---
    k_prep<<<8096, 256, 0, stream>>>(x, x8, cnt, w_in, wt_in8, w_mid, wt_mid8,
                                     w_out, wt_out8, fc1_w, wt_fc18, fc2_w, wt_fc2p8,
                                     qkv1_w, qkv1_8, qkv2_w, qkv2_8, qkv3_w, qkv3_8);

    // --- degree + CSR build ---
    k_count<<<EE / 256, 256, 0, stream>>>(ei, cnt);
    k_scan<<<1, 1024, 0, stream>>>(cnt, off, pos, dinv);
    k_fill<<<EE / 256, 256, 0, stream>>>(ei, dinv, pos, csrc, cw);

    auto layer = [&](const unsigned char* hin8, const unsigned char* wt8,
                     const float* b, int Kin) {
        // GCN (MX fp8): xw8 = hin @ w, aggregate -> g8 (fp8)
        gemm_mx<0, 10, 1><<<dim3(4, 64), 256, 0, stream>>>(
            hin8, wt8, nullptr, xw8, Kin, Kin, Kin, 512, 512, 0, 0, 0, 0);
        gcn_agg<<<NN, 256, 0, stream>>>(xw8, b, off, csrc, cw, dinv, g8);
        // qkv MLP (MX fp8): qkv1 wide M=3072, qkv2 z=3, qkv3 z=3 (v transposed)
        gemm_mx<1, 10, 1><<<dim3(24, 64), 256, 0, stream>>>(
            g8, qkv1_8, qkv1_b, t1_8, 512, 512, 512, 3072, 3072, 0, 0, 0, 0);
        gemm_mx<1, 10, 1><<<dim3(8, 64, 3), 256, 0, stream>>>(
            t1_8, qkv2_8, qkv2_b, t2_8, 1024, 3072, 1024, 3072, 1024,
            1024, 1048576, 1024, 1024);
        gemm_mx<1, 3, 1><<<dim3(4, 64, 3), 256, 0, stream>>>(
            t2_8, qkv3_8, qkv3_b, q8, 1024, 3072, 1024, 512, 512,
            1024, 524288, 4194304, 512);
        // fused attention: scores + softmax + AV -> h8 (fp8)
        attn_fused<<<NDOC, 256, 0, stream>>>(q8, k8, vt8, h8);
    };

    layer(x8, wt_in8, b_in, F_IN);
    layer(h8, wt_mid8, b_mid, DD);
    layer(h8, wt_mid8, b_mid, DD);
    layer(h8, wt_out8, b_out, DD);

    // final FCs (MX fp8) + pool + pairwise sigmoid
    gemm_mx<2, 10, 1><<<dim3(4, 64), 256, 0, stream>>>(
        h8, wt_fc18, fc1_b, x2_8, 512, 512, 512, 512, 512, 0, 0, 0, 0);
    gemm_mx<2, 0, 1><<<dim3(1, 64), 256, 0, stream>>>(
        x2_8, wt_fc2p8, fc2_b, h32, 512, 512, 512, 32, 32, 0, 0, 0, 0);
    pool_fc3<<<NDOC, 128, 0, stream>>>(h32, fc3_w, fc3_b, util);
    final_out<<<1, 64, 0, stream>>>(util, idx_a, idx_b, out);
}